// Round 12
// baseline (317.905 us; speedup 1.0000x reference)
//
#include <hip/hip_runtime.h>
#include <hip/hip_fp16.h>
#include <math.h>

#define B_  8
#define T_  4096
#define H_  512
#define FREQ 513
#define NW  576            // padded f (9 tiles of 64)
#define KE  576            // spec K: interleaved [re,im], padded; 9 tiles of 64
#define NFFT 1024
#define HOP 256
#define PAD 384
#define OUTB 1048576
#define CLAMP_MAXV 100.0f
#define SE_E ((size_t)T_ * KE)     // spec elems per batch (hi only)
#define EO_E ((size_t)T_ * NFFT)   // EO elems per batch

typedef __attribute__((ext_vector_type(8))) short bf16x8;
typedef __attribute__((ext_vector_type(4))) float f32x4;

__device__ inline ushort f2bf(float v) {
    union { float f; unsigned u; } x; x.f = v;
    unsigned r = x.u + 0x7FFFu + ((x.u >> 16) & 1u);   // RNE
    return (ushort)(r >> 16);
}
__device__ inline float bf2f(ushort h) {
    union { unsigned u; float f; } x; x.u = ((unsigned)h) << 16;
    return x.f;
}

#define GLOAD_LDS16(g, l) __builtin_amdgcn_global_load_lds( \
    (const __attribute__((address_space(1))) unsigned int*)(g), \
    (__attribute__((address_space(3))) unsigned int*)(l), 16, 0, 0)

// ---------------- basis: Ab[r][c]; r<512: E half (k=2kk), r>=512: O half (k=2kk+1) ----------------
__global__ void basis_kernel(ushort* __restrict__ Abh, ushort* __restrict__ Abl) {
    int idx = blockIdx.x * 256 + threadIdx.x;   // [0, 1024*576)
    int r = idx / KE, c = idx - r * KE;
    int np = (r < 512) ? r : (r - 512);
    int kk = c >> 1;
    int k = (r < 512) ? (2 * kk) : (2 * kk + 1);
    float v = 0.f;
    bool valid = (r < 512) ? (kk <= 256) : (kk <= 255);
    if (valid) {
        int m = (np * k) & (NFFT - 1);
        float a = (float)m * 6.135923151542565e-3f;       // 2*pi/1024
        float sc = ((k == 0) || (k == 512)) ? (1.0f / NFFT) : (2.0f / NFFT);
        v = ((c & 1) ? -sinf(a) : cosf(a)) * sc;
    }
    ushort h = f2bf(v);
    Abh[idx] = h;
    Abl[idx] = f2bf(v - bf2f(h));
}

// ---------------- W prep: Wm/Wp [f(576)][k(512)] hi/lo bf16 ----------------
__global__ void prepw_kernel(const float* __restrict__ W,
                             ushort* __restrict__ Wmh, ushort* __restrict__ Wml,
                             ushort* __restrict__ Wph, ushort* __restrict__ Wpl) {
    int idx = blockIdx.x * 256 + threadIdx.x;
    if (idx >= NW * H_) return;
    int k = idx / NW, f = idx - k * NW;
    float vm = 0.f, vp = 0.f;
    if (f < FREQ) {
        vm = W[(size_t)k * (2 * FREQ) + f];
        vp = W[(size_t)k * (2 * FREQ) + FREQ + f];
    }
    size_t dst = (size_t)f * H_ + k;
    ushort h1 = f2bf(vm); Wmh[dst] = h1; Wml[dst] = f2bf(vm - bf2f(h1));
    ushort h2 = f2bf(vp); Wph[dst] = h2; Wpl[dst] = f2bf(vp - bf2f(h2));
}

// ---------------- x conversion (hi only, per bcount-chunk): fp32 -> bf16 ----------------
__global__ void convx_kernel(const float* __restrict__ x, ushort* __restrict__ xh, int b0) {
    size_t i8 = ((size_t)blockIdx.x * 256 + threadIdx.x) * 8;
    const float* xp = x + (size_t)b0 * T_ * H_ + i8;
    float4 v0 = *reinterpret_cast<const float4*>(xp);
    float4 v1 = *reinterpret_cast<const float4*>(xp + 4);
    float xv[8];
    *reinterpret_cast<float4*>(&xv[0]) = v0;
    *reinterpret_cast<float4*>(&xv[4]) = v1;
    bf16x8 h;
    #pragma unroll
    for (int e = 0; e < 8; ++e) h[e] = (short)f2bf(xv[e]);
    *reinterpret_cast<bf16x8*>(xh + i8) = h;
}

// ---------------- GEMM A (MFMA): h = xh@(Wh+Wl) + b, tile 128t x 64f, K=512 ----------------
// grid: (bcount*32, 9); block 256 (4 waves 2x2). LDS 24.6KB -> 6 blocks/CU.
// Spec written TILED hi-only: buf[b][ftile][t][64].
__global__ __launch_bounds__(256) void gemm_a_mfma(
    const ushort* __restrict__ xh,
    const ushort* __restrict__ Wmh, const ushort* __restrict__ Wml,
    const ushort* __restrict__ Wph, const ushort* __restrict__ Wpl,
    const float* __restrict__ bias,
    ushort* __restrict__ SEh, ushort* __restrict__ SOh)
{
    // staging (ushort idx): xh @0 (4096), Wmh @4096, Wml @6144, Wph @8192, Wpl @10240
    // epilogue reuses [0, 9216) per pass. Total 12288 ushorts = 24576 B.
    __shared__ __attribute__((aligned(16))) ushort SH[12288];

    const int tid = threadIdx.x;
    const int lane = tid & 63;
    const int w = tid >> 6;
    const int wr = w >> 1, wc = w & 1;
    const int m0 = blockIdx.x * 128;     // chunk-local t row base
    const int f0 = blockIdx.y * 64;

    const int srow = tid >> 2;           // 0..63
    const int ssel = ((tid & 3) ^ ((tid >> 3) & 3)) * 8;
    const int arow = lane & 15;
    const int kch  = (((lane >> 4) ^ ((arow >> 1) & 3))) * 8;

    f32x4 accM[4][2] = {};
    f32x4 accP[4][2] = {};

    char* pSH = (char*)SH;

    for (int k0 = 0; k0 < H_; k0 += 32) {
        #pragma unroll
        for (int q = 0; q < 2; ++q) {
            size_t xo = (size_t)(m0 + q * 64 + srow) * H_ + k0 + ssel;
            GLOAD_LDS16(xh + xo, pSH + q * 4096 + w * 1024);
        }
        size_t wo = (size_t)(f0 + srow) * H_ + k0 + ssel;
        GLOAD_LDS16(Wmh + wo, pSH + 8192  + w * 1024);
        GLOAD_LDS16(Wml + wo, pSH + 12288 + w * 1024);
        GLOAD_LDS16(Wph + wo, pSH + 16384 + w * 1024);
        GLOAD_LDS16(Wpl + wo, pSH + 20480 + w * 1024);
        __syncthreads();
        bf16x8 ah[4], bmh[2], bml[2], bph[2], bpl[2];
        #pragma unroll
        for (int i = 0; i < 4; ++i) {
            int r = (wr * 64 + i * 16 + arow) * 32 + kch;
            ah[i] = *reinterpret_cast<const bf16x8*>(&SH[r]);
        }
        #pragma unroll
        for (int j = 0; j < 2; ++j) {
            int r = (wc * 32 + j * 16 + arow) * 32 + kch;
            bmh[j] = *reinterpret_cast<const bf16x8*>(&SH[4096 + r]);
            bml[j] = *reinterpret_cast<const bf16x8*>(&SH[6144 + r]);
            bph[j] = *reinterpret_cast<const bf16x8*>(&SH[8192 + r]);
            bpl[j] = *reinterpret_cast<const bf16x8*>(&SH[10240 + r]);
        }
        #pragma unroll
        for (int i = 0; i < 4; ++i)
            #pragma unroll
            for (int j = 0; j < 2; ++j) {
                accM[i][j] = __builtin_amdgcn_mfma_f32_16x16x32_bf16(ah[i], bmh[j], accM[i][j], 0, 0, 0);
                accM[i][j] = __builtin_amdgcn_mfma_f32_16x16x32_bf16(ah[i], bml[j], accM[i][j], 0, 0, 0);
                accP[i][j] = __builtin_amdgcn_mfma_f32_16x16x32_bf16(ah[i], bph[j], accP[i][j], 0, 0, 0);
                accP[i][j] = __builtin_amdgcn_mfma_f32_16x16x32_bf16(ah[i], bpl[j], accP[i][j], 0, 0, 0);
            }
        __syncthreads();
    }

    // ---- epilogue: nonlinearity in place, then 2-pass (SE, SO) LDS transpose ----
    const int ccol = lane & 15;
    const int rbase = (lane >> 4) * 4;
    const int b_local = m0 >> 12;
    const int t00blk = m0 & (T_ - 1);
    const size_t specoff = (size_t)b_local * SE_E;
    const size_t tilebase = (size_t)blockIdx.y * T_ * 64;

    #pragma unroll
    for (int j = 0; j < 2; ++j) {
        int f = f0 + wc * 32 + j * 16 + ccol;
        bool live = (f < FREQ);
        float bm = live ? bias[f] : 0.f;
        float bp = live ? bias[FREQ + f] : 0.f;
        #pragma unroll
        for (int i = 0; i < 4; ++i)
            #pragma unroll
            for (int r = 0; r < 4; ++r) {
                float re = 0.f, im = 0.f;
                if (live) {
                    float mag = fminf(__expf(accM[i][j][r] + bm), CLAMP_MAXV);
                    float phv = accP[i][j][r] + bp;
                    float sp, cp; __sincosf(phv, &sp, &cp);
                    re = mag * cp; im = mag * sp;
                }
                accM[i][j][r] = re; accP[i][j][r] = im;
            }
    }

    const int par_mine = ccol & 1;       // parity of this thread's u values
    const int row0 = tid >> 3;           // 0..31
    const int c8 = (tid & 7) * 8;
    #pragma unroll
    for (int pass = 0; pass < 2; ++pass) {
        if (par_mine == pass) {
            #pragma unroll
            for (int j = 0; j < 2; ++j) {
                int u = wc * 32 + j * 16 + ccol;
                int kl = u & ~1;
                #pragma unroll
                for (int i = 0; i < 4; ++i) {
                    #pragma unroll
                    for (int r = 0; r < 4; ++r) {
                        int tl = wr * 64 + i * 16 + rbase + r;
                        *reinterpret_cast<ushort2*>(&SH[tl * 72 + kl]) =
                            make_ushort2(f2bf(accM[i][j][r]), f2bf(accP[i][j][r]));
                    }
                }
            }
        }
        __syncthreads();
        ushort* d = (pass ? SOh : SEh) + specoff + tilebase;
        #pragma unroll
        for (int q2 = 0; q2 < 4; ++q2) {
            int row = q2 * 32 + row0;
            bf16x8 v = *reinterpret_cast<const bf16x8*>(&SH[row * 72 + c8]);
            *reinterpret_cast<bf16x8*>(&d[(size_t)(t00blk + row) * 64 + c8]) = v;
        }
        if (pass == 0) __syncthreads();
    }
}

// ---------------- stage 1 GEMM (MFMA, 2-term): EO[b][t][n''] = (Ah+Al).spec_hi, fp16 out -------
// grid: (64 t-tiles, 8 n-tiles, bcount); block 256 (4 waves 2x2). Tile 128n x 64t.
__global__ __launch_bounds__(256) void gemm_eo_mfma(
    const ushort* __restrict__ Abh, const ushort* __restrict__ Abl,
    const ushort* __restrict__ SEh, const ushort* __restrict__ SOh,
    __half* __restrict__ EO)
{
    __shared__ __attribute__((aligned(16))) ushort sAh[128 * 32];
    __shared__ __attribute__((aligned(16))) ushort sAl[128 * 32];
    __shared__ __attribute__((aligned(16))) ushort sBh[64 * 32];
    const int tid = threadIdx.x;
    const int lane = tid & 63;
    const int w = tid >> 6;
    const int wr = w >> 1, wc = w & 1;
    const int t0 = blockIdx.x * 64;
    const int n0 = blockIdx.y * 128;
    const int b_local = blockIdx.z;

    const ushort* Bsh = ((n0 < 512) ? SEh : SOh) + (size_t)b_local * SE_E;

    const int srow = tid >> 2;
    const int ssel = ((tid & 3) ^ ((tid >> 3) & 3)) * 8;
    const int arow = lane & 15;
    const int kch  = (((lane >> 4) ^ ((arow >> 1) & 3))) * 8;

    f32x4 acc[4][2] = {};
    char* pAh = (char*)sAh; char* pAl = (char*)sAl;
    char* pBh = (char*)sBh;

    for (int k0 = 0; k0 < KE; k0 += 32) {
        #pragma unroll
        for (int q = 0; q < 2; ++q) {
            size_t ao = (size_t)(n0 + q * 64 + srow) * KE + k0 + ssel;
            GLOAD_LDS16(Abh + ao, pAh + q * 4096 + w * 1024);
            GLOAD_LDS16(Abl + ao, pAl + q * 4096 + w * 1024);
        }
        size_t bo = ((size_t)(k0 >> 6) * T_ + t0 + srow) * 64 + (k0 & 32) + ssel;
        GLOAD_LDS16(Bsh + bo, pBh + w * 1024);
        __syncthreads();
        bf16x8 ah[4], al[4], bh[2];
        #pragma unroll
        for (int i = 0; i < 4; ++i) {
            int r = (wr * 64 + i * 16 + arow) * 32 + kch;
            ah[i] = *reinterpret_cast<const bf16x8*>(&sAh[r]);
            al[i] = *reinterpret_cast<const bf16x8*>(&sAl[r]);
        }
        #pragma unroll
        for (int j = 0; j < 2; ++j) {
            int r = (wc * 32 + j * 16 + arow) * 32 + kch;
            bh[j] = *reinterpret_cast<const bf16x8*>(&sBh[r]);
        }
        #pragma unroll
        for (int i = 0; i < 4; ++i)
            #pragma unroll
            for (int j = 0; j < 2; ++j) {
                acc[i][j] = __builtin_amdgcn_mfma_f32_16x16x32_bf16(ah[i], bh[j], acc[i][j], 0, 0, 0);
                acc[i][j] = __builtin_amdgcn_mfma_f32_16x16x32_bf16(al[i], bh[j], acc[i][j], 0, 0, 0);
            }
        __syncthreads();
    }

    // epilogue: C row = n'', col = t; EO[b][t][n''] as fp16, 8B stores
    const int ccol = lane & 15;
    const int rbase = (lane >> 4) * 4;
    __half* eob = EO + (size_t)b_local * EO_E;
    #pragma unroll
    for (int i = 0; i < 4; ++i) {
        int nb = n0 + wr * 64 + i * 16 + rbase;
        #pragma unroll
        for (int j = 0; j < 2; ++j) {
            int t = t0 + wc * 32 + j * 16 + ccol;
            __half hv[4];
            hv[0] = __float2half(acc[i][j][0]);
            hv[1] = __float2half(acc[i][j][1]);
            hv[2] = __float2half(acc[i][j][2]);
            hv[3] = __float2half(acc[i][j][3]);
            *reinterpret_cast<short4*>(&eob[(size_t)t * NFFT + nb]) =
                *reinterpret_cast<short4*>(hv);
        }
    }
}

// ---------------- gather: window * butterfly * OLA / env -> out ----------------
__global__ void gather_kernel(const __half* __restrict__ EO,
                              const float* __restrict__ window,
                              float* __restrict__ out, int b0, int bcount) {
    int o = blockIdx.x * 256 + threadIdx.x;
    int s = o + PAD;
    int m = s >> 8, p = s & 255;
    float env = 1e-11f;
    float wv[4]; int tv[4]; int np[4]; float sg[4];
    #pragma unroll
    for (int j = 0; j < 4; ++j) {
        int t = m - j;
        bool ok = (t >= 0) && (t < T_);
        tv[j] = ok ? t : 0;
        np[j] = p + 256 * (j & 1);
        sg[j] = (j < 2) ? 1.f : -1.f;
        float ww = ok ? window[p + 256 * j] : 0.f;
        wv[j] = ww;
        env += ww * ww;
    }
    float inv = 1.0f / env;
    for (int bl = 0; bl < bcount; ++bl) {
        const __half* eo = EO + (size_t)bl * EO_E;
        float y = 0.f;
        #pragma unroll
        for (int j = 0; j < 4; ++j) {
            const __half* row = eo + (size_t)tv[j] * NFFT;
            float e = __half2float(row[np[j]]);
            float od = __half2float(row[512 + np[j]]);
            y = fmaf(wv[j], fmaf(sg[j], od, e), y);
        }
        out[(size_t)(b0 + bl) * OUTB + o] = y * inv;
    }
}

// ---------------- launch ----------------
extern "C" void kernel_launch(void* const* d_in, const int* in_sizes, int n_in,
                              void* d_out, int out_size, void* d_ws, size_t ws_size,
                              hipStream_t stream) {
    const float* x      = (const float*)d_in[0];
    const float* W      = (const float*)d_in[1];
    const float* bias   = (const float*)d_in[2];
    const float* window = (const float*)d_in[3];
    float* out = (float*)d_out;

    const size_t Ae  = (size_t)NFFT * KE;        //   589,824
    const size_t We  = (size_t)NW * H_;          //   294,912

    // bcount: largest that fits. Layout: [A(2)|W(4)|spec hi E,O|EO(fp16)]
    // xh (bf16, bcount*T_*H_ = bcount*2M ushorts) aliases EO (bcount*4M halves) -- xh dead
    // once gemm_a finishes, before gemm_eo writes EO (stream-ordered).
    int bcount = B_;
    for (;;) {
        size_t need = (2 * Ae + 4 * We + 2 * (size_t)bcount * SE_E) * sizeof(ushort)
                    + (size_t)bcount * EO_E * sizeof(__half);
        if (need <= ws_size || bcount == 1) break;
        bcount >>= 1;
    }

    ushort* Abh = (ushort*)d_ws;
    ushort* Abl = Abh + Ae;
    ushort* Wmh = Abl + Ae;
    ushort* Wml = Wmh + We;
    ushort* Wph = Wml + We;
    ushort* Wpl = Wph + We;
    ushort* SEh = Wpl + We;
    ushort* SOh = SEh + (size_t)bcount * SE_E;
    __half* EO  = (__half*)(SOh + (size_t)bcount * SE_E);
    ushort* xhb = (ushort*)EO;                     // alias: xh lives in EO region

    basis_kernel<<<(NFFT * KE) / 256, 256, 0, stream>>>(Abh, Abl);
    prepw_kernel<<<(NW * H_ + 255) / 256, 256, 0, stream>>>(W, Wmh, Wml, Wph, Wpl);

    for (int b0 = 0; b0 < B_; b0 += bcount) {
        convx_kernel<<<(int)((size_t)bcount * T_ * H_ / 8 / 256), 256, 0, stream>>>(x, xhb, b0);
        dim3 ga(bcount * 32, 9);
        gemm_a_mfma<<<ga, 256, 0, stream>>>(xhb, Wmh, Wml, Wph, Wpl, bias, SEh, SOh);
        dim3 ge(64, 8, bcount);
        gemm_eo_mfma<<<ge, 256, 0, stream>>>(Abh, Abl, SEh, SOh, EO);
        gather_kernel<<<OUTB / 256, 256, 0, stream>>>(EO, window, out, b0, bcount);
    }
}

// Round 13
// 278.099 us; speedup vs baseline: 1.1431x; 1.1431x over previous
//
#include <hip/hip_runtime.h>
#include <hip/hip_fp16.h>
#include <math.h>

#define B_  8
#define T_  4096
#define H_  512
#define FREQ 513
#define NW  576            // padded f (9 tiles of 64)
#define KE  576            // spec K: interleaved [re,im], padded; 9 tiles of 64
#define NFFT 1024
#define HOP 256
#define PAD 384
#define OUTB 1048576
#define CLAMP_MAXV 100.0f
#define SE_E ((size_t)T_ * KE)     // spec elems per batch (hi only)
#define EO_E ((size_t)T_ * NFFT)   // EO elems per batch

typedef __attribute__((ext_vector_type(8))) short bf16x8;
typedef __attribute__((ext_vector_type(4))) float f32x4;

__device__ inline ushort f2bf(float v) {
    union { float f; unsigned u; } x; x.f = v;
    unsigned r = x.u + 0x7FFFu + ((x.u >> 16) & 1u);   // RNE
    return (ushort)(r >> 16);
}
__device__ inline float bf2f(ushort h) {
    union { unsigned u; float f; } x; x.u = ((unsigned)h) << 16;
    return x.f;
}

#define GLOAD_LDS16(g, l) __builtin_amdgcn_global_load_lds( \
    (const __attribute__((address_space(1))) unsigned int*)(g), \
    (__attribute__((address_space(3))) unsigned int*)(l), 16, 0, 0)

// ---------------- basis: Ab[r][c]; r<512: E half (k=2kk), r>=512: O half (k=2kk+1) ----------------
__global__ void basis_kernel(ushort* __restrict__ Abh, ushort* __restrict__ Abl) {
    int idx = blockIdx.x * 256 + threadIdx.x;   // [0, 1024*576)
    int r = idx / KE, c = idx - r * KE;
    int np = (r < 512) ? r : (r - 512);
    int kk = c >> 1;
    int k = (r < 512) ? (2 * kk) : (2 * kk + 1);
    float v = 0.f;
    bool valid = (r < 512) ? (kk <= 256) : (kk <= 255);
    if (valid) {
        int m = (np * k) & (NFFT - 1);
        float a = (float)m * 6.135923151542565e-3f;       // 2*pi/1024
        float sc = ((k == 0) || (k == 512)) ? (1.0f / NFFT) : (2.0f / NFFT);
        v = ((c & 1) ? -sinf(a) : cosf(a)) * sc;
    }
    ushort h = f2bf(v);
    Abh[idx] = h;
    Abl[idx] = f2bf(v - bf2f(h));
}

// ---------------- W prep: Wm/Wp [f(576)][k(512)] hi/lo bf16 ----------------
__global__ void prepw_kernel(const float* __restrict__ W,
                             ushort* __restrict__ Wmh, ushort* __restrict__ Wml,
                             ushort* __restrict__ Wph, ushort* __restrict__ Wpl) {
    int idx = blockIdx.x * 256 + threadIdx.x;
    if (idx >= NW * H_) return;
    int k = idx / NW, f = idx - k * NW;
    float vm = 0.f, vp = 0.f;
    if (f < FREQ) {
        vm = W[(size_t)k * (2 * FREQ) + f];
        vp = W[(size_t)k * (2 * FREQ) + FREQ + f];
    }
    size_t dst = (size_t)f * H_ + k;
    ushort h1 = f2bf(vm); Wmh[dst] = h1; Wml[dst] = f2bf(vm - bf2f(h1));
    ushort h2 = f2bf(vp); Wph[dst] = h2; Wpl[dst] = f2bf(vp - bf2f(h2));
}

// ---------------- GEMM A (MFMA): h = xh@(Wh+Wl) + b, tile 128t x 64f, K=512 ----------------
// grid: (bcount*32, 9); block 256 (4 waves 2x2). LDS 24.6KB -> 6 blocks/CU.
// x fp32 reg-staged + in-register hi-bf16 convert (ILP hides staging latency).
// Spec written TILED hi-only: buf[b][ftile][t][64].
__global__ __launch_bounds__(256) void gemm_a_mfma(
    const float* __restrict__ x,
    const ushort* __restrict__ Wmh, const ushort* __restrict__ Wml,
    const ushort* __restrict__ Wph, const ushort* __restrict__ Wpl,
    const float* __restrict__ bias,
    ushort* __restrict__ SEh, ushort* __restrict__ SOh, int b0)
{
    // staging (ushort idx): xh @0 (4096), Wmh @4096, Wml @6144, Wph @8192, Wpl @10240
    // epilogue reuses [0, 9216) per pass. Total 12288 ushorts = 24576 B.
    __shared__ __attribute__((aligned(16))) ushort SH[12288];

    const int tid = threadIdx.x;
    const int lane = tid & 63;
    const int w = tid >> 6;
    const int wr = w >> 1, wc = w & 1;
    const int m0 = blockIdx.x * 128;     // chunk-local t row base
    const int f0 = blockIdx.y * 64;

    const int srow = tid >> 2;           // 0..63
    const int ssel = ((tid & 3) ^ ((tid >> 3) & 3)) * 8;
    const int arow = lane & 15;
    const int kch  = (((lane >> 4) ^ ((arow >> 1) & 3))) * 8;
    const int xcol = (tid & 3) * 8;

    f32x4 accM[4][2] = {};
    f32x4 accP[4][2] = {};

    const size_t xbase = (size_t)b0 * T_ + m0;
    char* pSH = (char*)SH;

    for (int k0 = 0; k0 < H_; k0 += 32) {
        // x: global fp32 -> regs (issue early)
        float4 xa[2][2];
        #pragma unroll
        for (int q = 0; q < 2; ++q) {
            const float* xr = x + (xbase + q * 64 + srow) * H_ + k0 + xcol;
            xa[q][0] = *reinterpret_cast<const float4*>(xr);
            xa[q][1] = *reinterpret_cast<const float4*>(xr + 4);
        }
        // W: global -> LDS direct (source pre-swizzled)
        size_t wo = (size_t)(f0 + srow) * H_ + k0 + ssel;
        GLOAD_LDS16(Wmh + wo, pSH + 8192  + w * 1024);
        GLOAD_LDS16(Wml + wo, pSH + 12288 + w * 1024);
        GLOAD_LDS16(Wph + wo, pSH + 16384 + w * 1024);
        GLOAD_LDS16(Wpl + wo, pSH + 20480 + w * 1024);
        // convert x -> hi bf16 only, ds_write swizzled
        #pragma unroll
        for (int q = 0; q < 2; ++q) {
            float xv[8];
            *reinterpret_cast<float4*>(&xv[0]) = xa[q][0];
            *reinterpret_cast<float4*>(&xv[4]) = xa[q][1];
            bf16x8 vh;
            #pragma unroll
            for (int e = 0; e < 8; ++e) vh[e] = (short)f2bf(xv[e]);
            int lo = (q * 64 + srow) * 32 + ssel;
            *reinterpret_cast<bf16x8*>(&SH[lo]) = vh;
        }
        __syncthreads();
        bf16x8 ah[4], bmh[2], bml[2], bph[2], bpl[2];
        #pragma unroll
        for (int i = 0; i < 4; ++i) {
            int r = (wr * 64 + i * 16 + arow) * 32 + kch;
            ah[i] = *reinterpret_cast<const bf16x8*>(&SH[r]);
        }
        #pragma unroll
        for (int j = 0; j < 2; ++j) {
            int r = (wc * 32 + j * 16 + arow) * 32 + kch;
            bmh[j] = *reinterpret_cast<const bf16x8*>(&SH[4096 + r]);
            bml[j] = *reinterpret_cast<const bf16x8*>(&SH[6144 + r]);
            bph[j] = *reinterpret_cast<const bf16x8*>(&SH[8192 + r]);
            bpl[j] = *reinterpret_cast<const bf16x8*>(&SH[10240 + r]);
        }
        #pragma unroll
        for (int i = 0; i < 4; ++i)
            #pragma unroll
            for (int j = 0; j < 2; ++j) {
                accM[i][j] = __builtin_amdgcn_mfma_f32_16x16x32_bf16(ah[i], bmh[j], accM[i][j], 0, 0, 0);
                accM[i][j] = __builtin_amdgcn_mfma_f32_16x16x32_bf16(ah[i], bml[j], accM[i][j], 0, 0, 0);
                accP[i][j] = __builtin_amdgcn_mfma_f32_16x16x32_bf16(ah[i], bph[j], accP[i][j], 0, 0, 0);
                accP[i][j] = __builtin_amdgcn_mfma_f32_16x16x32_bf16(ah[i], bpl[j], accP[i][j], 0, 0, 0);
            }
        __syncthreads();
    }

    // ---- epilogue: nonlinearity in place, then 2-pass (SE, SO) LDS transpose ----
    const int ccol = lane & 15;
    const int rbase = (lane >> 4) * 4;
    const int b_local = m0 >> 12;
    const int t00blk = m0 & (T_ - 1);
    const size_t specoff = (size_t)b_local * SE_E;
    const size_t tilebase = (size_t)blockIdx.y * T_ * 64;

    #pragma unroll
    for (int j = 0; j < 2; ++j) {
        int f = f0 + wc * 32 + j * 16 + ccol;
        bool live = (f < FREQ);
        float bm = live ? bias[f] : 0.f;
        float bp = live ? bias[FREQ + f] : 0.f;
        #pragma unroll
        for (int i = 0; i < 4; ++i)
            #pragma unroll
            for (int r = 0; r < 4; ++r) {
                float re = 0.f, im = 0.f;
                if (live) {
                    float mag = fminf(__expf(accM[i][j][r] + bm), CLAMP_MAXV);
                    float phv = accP[i][j][r] + bp;
                    float sp, cp; __sincosf(phv, &sp, &cp);
                    re = mag * cp; im = mag * sp;
                }
                accM[i][j][r] = re; accP[i][j][r] = im;
            }
    }

    const int par_mine = ccol & 1;       // parity of this thread's u values
    const int row0 = tid >> 3;           // 0..31
    const int c8 = (tid & 7) * 8;
    #pragma unroll
    for (int pass = 0; pass < 2; ++pass) {
        if (par_mine == pass) {
            #pragma unroll
            for (int j = 0; j < 2; ++j) {
                int u = wc * 32 + j * 16 + ccol;
                int kl = u & ~1;
                #pragma unroll
                for (int i = 0; i < 4; ++i) {
                    #pragma unroll
                    for (int r = 0; r < 4; ++r) {
                        int tl = wr * 64 + i * 16 + rbase + r;
                        *reinterpret_cast<ushort2*>(&SH[tl * 72 + kl]) =
                            make_ushort2(f2bf(accM[i][j][r]), f2bf(accP[i][j][r]));
                    }
                }
            }
        }
        __syncthreads();
        ushort* d = (pass ? SOh : SEh) + specoff + tilebase;
        #pragma unroll
        for (int q2 = 0; q2 < 4; ++q2) {
            int row = q2 * 32 + row0;
            bf16x8 v = *reinterpret_cast<const bf16x8*>(&SH[row * 72 + c8]);
            *reinterpret_cast<bf16x8*>(&d[(size_t)(t00blk + row) * 64 + c8]) = v;
        }
        if (pass == 0) __syncthreads();
    }
}

// ---------------- stage 1 GEMM (MFMA, 2-term): EO[b][t][n''] = (Ah+Al).spec_hi, fp16 out -------
// grid: (64 t-tiles, 8 n-tiles, bcount); block 256 (4 waves 2x2). Tile 128n x 64t.
__global__ __launch_bounds__(256) void gemm_eo_mfma(
    const ushort* __restrict__ Abh, const ushort* __restrict__ Abl,
    const ushort* __restrict__ SEh, const ushort* __restrict__ SOh,
    __half* __restrict__ EO)
{
    __shared__ __attribute__((aligned(16))) ushort sAh[128 * 32];
    __shared__ __attribute__((aligned(16))) ushort sAl[128 * 32];
    __shared__ __attribute__((aligned(16))) ushort sBh[64 * 32];
    const int tid = threadIdx.x;
    const int lane = tid & 63;
    const int w = tid >> 6;
    const int wr = w >> 1, wc = w & 1;
    const int t0 = blockIdx.x * 64;
    const int n0 = blockIdx.y * 128;
    const int b_local = blockIdx.z;

    const ushort* Bsh = ((n0 < 512) ? SEh : SOh) + (size_t)b_local * SE_E;

    const int srow = tid >> 2;
    const int ssel = ((tid & 3) ^ ((tid >> 3) & 3)) * 8;
    const int arow = lane & 15;
    const int kch  = (((lane >> 4) ^ ((arow >> 1) & 3))) * 8;

    f32x4 acc[4][2] = {};
    char* pAh = (char*)sAh; char* pAl = (char*)sAl;
    char* pBh = (char*)sBh;

    for (int k0 = 0; k0 < KE; k0 += 32) {
        #pragma unroll
        for (int q = 0; q < 2; ++q) {
            size_t ao = (size_t)(n0 + q * 64 + srow) * KE + k0 + ssel;
            GLOAD_LDS16(Abh + ao, pAh + q * 4096 + w * 1024);
            GLOAD_LDS16(Abl + ao, pAl + q * 4096 + w * 1024);
        }
        size_t bo = ((size_t)(k0 >> 6) * T_ + t0 + srow) * 64 + (k0 & 32) + ssel;
        GLOAD_LDS16(Bsh + bo, pBh + w * 1024);
        __syncthreads();
        bf16x8 ah[4], al[4], bh[2];
        #pragma unroll
        for (int i = 0; i < 4; ++i) {
            int r = (wr * 64 + i * 16 + arow) * 32 + kch;
            ah[i] = *reinterpret_cast<const bf16x8*>(&sAh[r]);
            al[i] = *reinterpret_cast<const bf16x8*>(&sAl[r]);
        }
        #pragma unroll
        for (int j = 0; j < 2; ++j) {
            int r = (wc * 32 + j * 16 + arow) * 32 + kch;
            bh[j] = *reinterpret_cast<const bf16x8*>(&sBh[r]);
        }
        #pragma unroll
        for (int i = 0; i < 4; ++i)
            #pragma unroll
            for (int j = 0; j < 2; ++j) {
                acc[i][j] = __builtin_amdgcn_mfma_f32_16x16x32_bf16(ah[i], bh[j], acc[i][j], 0, 0, 0);
                acc[i][j] = __builtin_amdgcn_mfma_f32_16x16x32_bf16(al[i], bh[j], acc[i][j], 0, 0, 0);
            }
        __syncthreads();
    }

    // epilogue: C row = n'', col = t; EO[b][t][n''] as fp16, 8B stores
    const int ccol = lane & 15;
    const int rbase = (lane >> 4) * 4;
    __half* eob = EO + (size_t)b_local * EO_E;
    #pragma unroll
    for (int i = 0; i < 4; ++i) {
        int nb = n0 + wr * 64 + i * 16 + rbase;
        #pragma unroll
        for (int j = 0; j < 2; ++j) {
            int t = t0 + wc * 32 + j * 16 + ccol;
            __half hv[4];
            hv[0] = __float2half(acc[i][j][0]);
            hv[1] = __float2half(acc[i][j][1]);
            hv[2] = __float2half(acc[i][j][2]);
            hv[3] = __float2half(acc[i][j][3]);
            *reinterpret_cast<short4*>(&eob[(size_t)t * NFFT + nb]) =
                *reinterpret_cast<short4*>(hv);
        }
    }
}

// ---------------- gather: window * butterfly * OLA / env -> out ----------------
__global__ void gather_kernel(const __half* __restrict__ EO,
                              const float* __restrict__ window,
                              float* __restrict__ out, int b0, int bcount) {
    int o = blockIdx.x * 256 + threadIdx.x;
    int s = o + PAD;
    int m = s >> 8, p = s & 255;
    float env = 1e-11f;
    float wv[4]; int tv[4]; int np[4]; float sg[4];
    #pragma unroll
    for (int j = 0; j < 4; ++j) {
        int t = m - j;
        bool ok = (t >= 0) && (t < T_);
        tv[j] = ok ? t : 0;
        np[j] = p + 256 * (j & 1);
        sg[j] = (j < 2) ? 1.f : -1.f;
        float ww = ok ? window[p + 256 * j] : 0.f;
        wv[j] = ww;
        env += ww * ww;
    }
    float inv = 1.0f / env;
    for (int bl = 0; bl < bcount; ++bl) {
        const __half* eo = EO + (size_t)bl * EO_E;
        float y = 0.f;
        #pragma unroll
        for (int j = 0; j < 4; ++j) {
            const __half* row = eo + (size_t)tv[j] * NFFT;
            float e = __half2float(row[np[j]]);
            float od = __half2float(row[512 + np[j]]);
            y = fmaf(wv[j], fmaf(sg[j], od, e), y);
        }
        out[(size_t)(b0 + bl) * OUTB + o] = y * inv;
    }
}

// ---------------- launch ----------------
extern "C" void kernel_launch(void* const* d_in, const int* in_sizes, int n_in,
                              void* d_out, int out_size, void* d_ws, size_t ws_size,
                              hipStream_t stream) {
    const float* x      = (const float*)d_in[0];
    const float* W      = (const float*)d_in[1];
    const float* bias   = (const float*)d_in[2];
    const float* window = (const float*)d_in[3];
    float* out = (float*)d_out;

    const size_t Ae  = (size_t)NFFT * KE;        //   589,824
    const size_t We  = (size_t)NW * H_;          //   294,912

    // bcount: largest that fits. Layout: [A(2)|W(4)|spec hi E,O|EO(fp16)]
    int bcount = B_;
    for (;;) {
        size_t need = (2 * Ae + 4 * We + 2 * (size_t)bcount * SE_E) * sizeof(ushort)
                    + (size_t)bcount * EO_E * sizeof(__half);
        if (need <= ws_size || bcount == 1) break;
        bcount >>= 1;
    }

    ushort* Abh = (ushort*)d_ws;
    ushort* Abl = Abh + Ae;
    ushort* Wmh = Abl + Ae;
    ushort* Wml = Wmh + We;
    ushort* Wph = Wml + We;
    ushort* Wpl = Wph + We;
    ushort* SEh = Wpl + We;
    ushort* SOh = SEh + (size_t)bcount * SE_E;
    __half* EO  = (__half*)(SOh + (size_t)bcount * SE_E);

    basis_kernel<<<(NFFT * KE) / 256, 256, 0, stream>>>(Abh, Abl);
    prepw_kernel<<<(NW * H_ + 255) / 256, 256, 0, stream>>>(W, Wmh, Wml, Wph, Wpl);

    for (int b0 = 0; b0 < B_; b0 += bcount) {
        dim3 ga(bcount * 32, 9);
        gemm_a_mfma<<<ga, 256, 0, stream>>>(x, Wmh, Wml, Wph, Wpl, bias, SEh, SOh, b0);
        dim3 ge(64, 8, bcount);
        gemm_eo_mfma<<<ge, 256, 0, stream>>>(Abh, Abl, SEh, SOh, EO);
        gather_kernel<<<OUTB / 256, 256, 0, stream>>>(EO, window, out, b0, bcount);
    }
}

// Round 14
// 259.856 us; speedup vs baseline: 1.2234x; 1.0702x over previous
//
#include <hip/hip_runtime.h>
#include <hip/hip_fp16.h>
#include <math.h>

#define B_  8
#define T_  4096
#define H_  512
#define FREQ 513
#define NW  576            // padded f (9 tiles of 64)
#define KE  576            // spec K: interleaved [re,im], padded; 9 tiles of 64
#define NFFT 1024
#define HOP 256
#define PAD 384
#define OUTB 1048576
#define CLAMP_MAXV 100.0f
#define SE_E ((size_t)T_ * KE)     // spec elems per batch (hi only)
#define EO_E ((size_t)T_ * NFFT)   // EO elems per batch

typedef __attribute__((ext_vector_type(8))) short bf16x8;
typedef __attribute__((ext_vector_type(4))) float f32x4;

__device__ inline ushort f2bf(float v) {
    union { float f; unsigned u; } x; x.f = v;
    unsigned r = x.u + 0x7FFFu + ((x.u >> 16) & 1u);   // RNE
    return (ushort)(r >> 16);
}
__device__ inline float bf2f(ushort h) {
    union { unsigned u; float f; } x; x.u = ((unsigned)h) << 16;
    return x.f;
}

#define GLOAD_LDS16(g, l) __builtin_amdgcn_global_load_lds( \
    (const __attribute__((address_space(1))) unsigned int*)(g), \
    (__attribute__((address_space(3))) unsigned int*)(l), 16, 0, 0)

// ---------------- basis: Ab[r][c]; r<512: E half (k=2kk), r>=512: O half (k=2kk+1) ----------------
__global__ void basis_kernel(ushort* __restrict__ Abh, ushort* __restrict__ Abl) {
    int idx = blockIdx.x * 256 + threadIdx.x;   // [0, 1024*576)
    int r = idx / KE, c = idx - r * KE;
    int np = (r < 512) ? r : (r - 512);
    int kk = c >> 1;
    int k = (r < 512) ? (2 * kk) : (2 * kk + 1);
    float v = 0.f;
    bool valid = (r < 512) ? (kk <= 256) : (kk <= 255);
    if (valid) {
        int m = (np * k) & (NFFT - 1);
        float a = (float)m * 6.135923151542565e-3f;       // 2*pi/1024
        float sc = ((k == 0) || (k == 512)) ? (1.0f / NFFT) : (2.0f / NFFT);
        v = ((c & 1) ? -sinf(a) : cosf(a)) * sc;
    }
    ushort h = f2bf(v);
    Abh[idx] = h;
    Abl[idx] = f2bf(v - bf2f(h));
}

// ---------------- W prep: Wm/Wp [f(576)][k(512)] hi/lo bf16 ----------------
__global__ void prepw_kernel(const float* __restrict__ W,
                             ushort* __restrict__ Wmh, ushort* __restrict__ Wml,
                             ushort* __restrict__ Wph, ushort* __restrict__ Wpl) {
    int idx = blockIdx.x * 256 + threadIdx.x;
    if (idx >= NW * H_) return;
    int k = idx / NW, f = idx - k * NW;
    float vm = 0.f, vp = 0.f;
    if (f < FREQ) {
        vm = W[(size_t)k * (2 * FREQ) + f];
        vp = W[(size_t)k * (2 * FREQ) + FREQ + f];
    }
    size_t dst = (size_t)f * H_ + k;
    ushort h1 = f2bf(vm); Wmh[dst] = h1; Wml[dst] = f2bf(vm - bf2f(h1));
    ushort h2 = f2bf(vp); Wph[dst] = h2; Wpl[dst] = f2bf(vp - bf2f(h2));
}

// ---------------- x conversion (hi only, per bcount-chunk): fp32 -> bf16 ----------------
__global__ void convx_kernel(const float* __restrict__ x, ushort* __restrict__ xh, int b0) {
    size_t i8 = ((size_t)blockIdx.x * 256 + threadIdx.x) * 8;
    const float* xp = x + (size_t)b0 * T_ * H_ + i8;
    float4 v0 = *reinterpret_cast<const float4*>(xp);
    float4 v1 = *reinterpret_cast<const float4*>(xp + 4);
    float xv[8];
    *reinterpret_cast<float4*>(&xv[0]) = v0;
    *reinterpret_cast<float4*>(&xv[4]) = v1;
    bf16x8 h;
    #pragma unroll
    for (int e = 0; e < 8; ++e) h[e] = (short)f2bf(xv[e]);
    *reinterpret_cast<bf16x8*>(xh + i8) = h;
}

// ---------------- GEMM A (MFMA): h = xh@(Wh+Wl) + b, tile 128t x 64f, K=512 ----------------
// grid: 1D bcount*288, XCD-swizzled (f fastest within an XCD slot run).
// x bf16 reg-staged -> ds_write (keeps ILP); W via global_load_lds.
__global__ __launch_bounds__(256) void gemm_a_mfma(
    const ushort* __restrict__ xh,
    const ushort* __restrict__ Wmh, const ushort* __restrict__ Wml,
    const ushort* __restrict__ Wph, const ushort* __restrict__ Wpl,
    const float* __restrict__ bias,
    ushort* __restrict__ SEh, ushort* __restrict__ SOh)
{
    // staging (ushort idx): xh @0 (4096), Wmh @4096, Wml @6144, Wph @8192, Wpl @10240
    // epilogue reuses [0, 9216) per pass. Total 12288 ushorts = 24576 B.
    __shared__ __attribute__((aligned(16))) ushort SH[12288];

    const int tid = threadIdx.x;
    const int lane = tid & 63;
    const int w = tid >> 6;
    const int wr = w >> 1, wc = w & 1;

    // XCD swizzle: wg%8 = physical XCD; give each XCD contiguous t-tiles, f fastest
    const int nwg = gridDim.x;                 // bcount*288, % 8 == 0
    const int wg = blockIdx.x;
    const int gwi = (wg & 7) * (nwg >> 3) + (wg >> 3);
    const int m0 = (gwi / 9) * 128;            // chunk-local t row base
    const int f0 = (gwi % 9) * 64;

    const int srow = tid >> 2;           // 0..63
    const int ssel = ((tid & 3) ^ ((tid >> 3) & 3)) * 8;
    const int arow = lane & 15;
    const int kch  = (((lane >> 4) ^ ((arow >> 1) & 3))) * 8;
    const int xcol = (tid & 3) * 8;

    f32x4 accM[4][2] = {};
    f32x4 accP[4][2] = {};

    char* pSH = (char*)SH;

    for (int k0 = 0; k0 < H_; k0 += 32) {
        // x: bf16 global -> regs (issue early)
        bf16x8 xv[2];
        #pragma unroll
        for (int q = 0; q < 2; ++q)
            xv[q] = *reinterpret_cast<const bf16x8*>(
                &xh[(size_t)(m0 + q * 64 + srow) * H_ + k0 + xcol]);
        // W: global -> LDS direct (source pre-swizzled)
        size_t wo = (size_t)(f0 + srow) * H_ + k0 + ssel;
        GLOAD_LDS16(Wmh + wo, pSH + 8192  + w * 1024);
        GLOAD_LDS16(Wml + wo, pSH + 12288 + w * 1024);
        GLOAD_LDS16(Wph + wo, pSH + 16384 + w * 1024);
        GLOAD_LDS16(Wpl + wo, pSH + 20480 + w * 1024);
        // x -> LDS swizzled (pass-through)
        #pragma unroll
        for (int q = 0; q < 2; ++q)
            *reinterpret_cast<bf16x8*>(&SH[(q * 64 + srow) * 32 + ssel]) = xv[q];
        __syncthreads();
        bf16x8 ah[4], bmh[2], bml[2], bph[2], bpl[2];
        #pragma unroll
        for (int i = 0; i < 4; ++i) {
            int r = (wr * 64 + i * 16 + arow) * 32 + kch;
            ah[i] = *reinterpret_cast<const bf16x8*>(&SH[r]);
        }
        #pragma unroll
        for (int j = 0; j < 2; ++j) {
            int r = (wc * 32 + j * 16 + arow) * 32 + kch;
            bmh[j] = *reinterpret_cast<const bf16x8*>(&SH[4096 + r]);
            bml[j] = *reinterpret_cast<const bf16x8*>(&SH[6144 + r]);
            bph[j] = *reinterpret_cast<const bf16x8*>(&SH[8192 + r]);
            bpl[j] = *reinterpret_cast<const bf16x8*>(&SH[10240 + r]);
        }
        #pragma unroll
        for (int i = 0; i < 4; ++i)
            #pragma unroll
            for (int j = 0; j < 2; ++j) {
                accM[i][j] = __builtin_amdgcn_mfma_f32_16x16x32_bf16(ah[i], bmh[j], accM[i][j], 0, 0, 0);
                accM[i][j] = __builtin_amdgcn_mfma_f32_16x16x32_bf16(ah[i], bml[j], accM[i][j], 0, 0, 0);
                accP[i][j] = __builtin_amdgcn_mfma_f32_16x16x32_bf16(ah[i], bph[j], accP[i][j], 0, 0, 0);
                accP[i][j] = __builtin_amdgcn_mfma_f32_16x16x32_bf16(ah[i], bpl[j], accP[i][j], 0, 0, 0);
            }
        __syncthreads();
    }

    // ---- epilogue: nonlinearity in place, then 2-pass (SE, SO) LDS transpose ----
    const int ccol = lane & 15;
    const int rbase = (lane >> 4) * 4;
    const int b_local = m0 >> 12;
    const int t00blk = m0 & (T_ - 1);
    const size_t specoff = (size_t)b_local * SE_E;
    const size_t tilebase = (size_t)(f0 >> 6) * T_ * 64;

    #pragma unroll
    for (int j = 0; j < 2; ++j) {
        int f = f0 + wc * 32 + j * 16 + ccol;
        bool live = (f < FREQ);
        float bm = live ? bias[f] : 0.f;
        float bp = live ? bias[FREQ + f] : 0.f;
        #pragma unroll
        for (int i = 0; i < 4; ++i)
            #pragma unroll
            for (int r = 0; r < 4; ++r) {
                float re = 0.f, im = 0.f;
                if (live) {
                    float mag = fminf(__expf(accM[i][j][r] + bm), CLAMP_MAXV);
                    float phv = accP[i][j][r] + bp;
                    float sp, cp; __sincosf(phv, &sp, &cp);
                    re = mag * cp; im = mag * sp;
                }
                accM[i][j][r] = re; accP[i][j][r] = im;
            }
    }

    const int par_mine = ccol & 1;       // parity of this thread's u values
    const int row0 = tid >> 3;           // 0..31
    const int c8 = (tid & 7) * 8;
    #pragma unroll
    for (int pass = 0; pass < 2; ++pass) {
        if (par_mine == pass) {
            #pragma unroll
            for (int j = 0; j < 2; ++j) {
                int u = wc * 32 + j * 16 + ccol;
                int kl = u & ~1;
                #pragma unroll
                for (int i = 0; i < 4; ++i) {
                    #pragma unroll
                    for (int r = 0; r < 4; ++r) {
                        int tl = wr * 64 + i * 16 + rbase + r;
                        *reinterpret_cast<ushort2*>(&SH[tl * 72 + kl]) =
                            make_ushort2(f2bf(accM[i][j][r]), f2bf(accP[i][j][r]));
                    }
                }
            }
        }
        __syncthreads();
        ushort* d = (pass ? SOh : SEh) + specoff + tilebase;
        #pragma unroll
        for (int q2 = 0; q2 < 4; ++q2) {
            int row = q2 * 32 + row0;
            bf16x8 v = *reinterpret_cast<const bf16x8*>(&SH[row * 72 + c8]);
            *reinterpret_cast<bf16x8*>(&d[(size_t)(t00blk + row) * 64 + c8]) = v;
        }
        if (pass == 0) __syncthreads();
    }
}

// ---------------- stage 1 GEMM (MFMA, 2-term): EO[b][t][n''] = (Ah+Al).spec_hi, fp16 out -------
// grid: (512, bcount), XCD-swizzled (n fastest within an XCD slot run). Tile 128n x 64t.
__global__ __launch_bounds__(256) void gemm_eo_mfma(
    const ushort* __restrict__ Abh, const ushort* __restrict__ Abl,
    const ushort* __restrict__ SEh, const ushort* __restrict__ SOh,
    __half* __restrict__ EO)
{
    __shared__ __attribute__((aligned(16))) ushort sAh[128 * 32];
    __shared__ __attribute__((aligned(16))) ushort sAl[128 * 32];
    __shared__ __attribute__((aligned(16))) ushort sBh[64 * 32];
    const int tid = threadIdx.x;
    const int lane = tid & 63;
    const int w = tid >> 6;
    const int wr = w >> 1, wc = w & 1;

    const int wg = blockIdx.x;                 // 512 = 64t x 8n, % 8 == 0
    const int gwi = (wg & 7) * 64 + (wg >> 3);
    const int t0 = (gwi >> 3) * 64;            // contiguous t per XCD
    const int n0 = (gwi & 7) * 128;            // n fastest
    const int b_local = blockIdx.y;

    const ushort* Bsh = ((n0 < 512) ? SEh : SOh) + (size_t)b_local * SE_E;

    const int srow = tid >> 2;
    const int ssel = ((tid & 3) ^ ((tid >> 3) & 3)) * 8;
    const int arow = lane & 15;
    const int kch  = (((lane >> 4) ^ ((arow >> 1) & 3))) * 8;

    f32x4 acc[4][2] = {};
    char* pAh = (char*)sAh; char* pAl = (char*)sAl;
    char* pBh = (char*)sBh;

    for (int k0 = 0; k0 < KE; k0 += 32) {
        #pragma unroll
        for (int q = 0; q < 2; ++q) {
            size_t ao = (size_t)(n0 + q * 64 + srow) * KE + k0 + ssel;
            GLOAD_LDS16(Abh + ao, pAh + q * 4096 + w * 1024);
            GLOAD_LDS16(Abl + ao, pAl + q * 4096 + w * 1024);
        }
        size_t bo = ((size_t)(k0 >> 6) * T_ + t0 + srow) * 64 + (k0 & 32) + ssel;
        GLOAD_LDS16(Bsh + bo, pBh + w * 1024);
        __syncthreads();
        bf16x8 ah[4], al[4], bh[2];
        #pragma unroll
        for (int i = 0; i < 4; ++i) {
            int r = (wr * 64 + i * 16 + arow) * 32 + kch;
            ah[i] = *reinterpret_cast<const bf16x8*>(&sAh[r]);
            al[i] = *reinterpret_cast<const bf16x8*>(&sAl[r]);
        }
        #pragma unroll
        for (int j = 0; j < 2; ++j) {
            int r = (wc * 32 + j * 16 + arow) * 32 + kch;
            bh[j] = *reinterpret_cast<const bf16x8*>(&sBh[r]);
        }
        #pragma unroll
        for (int i = 0; i < 4; ++i)
            #pragma unroll
            for (int j = 0; j < 2; ++j) {
                acc[i][j] = __builtin_amdgcn_mfma_f32_16x16x32_bf16(ah[i], bh[j], acc[i][j], 0, 0, 0);
                acc[i][j] = __builtin_amdgcn_mfma_f32_16x16x32_bf16(al[i], bh[j], acc[i][j], 0, 0, 0);
            }
        __syncthreads();
    }

    // epilogue: C row = n'', col = t; EO[b][t][n''] as fp16, 8B stores
    const int ccol = lane & 15;
    const int rbase = (lane >> 4) * 4;
    __half* eob = EO + (size_t)b_local * EO_E;
    #pragma unroll
    for (int i = 0; i < 4; ++i) {
        int nb = n0 + wr * 64 + i * 16 + rbase;
        #pragma unroll
        for (int j = 0; j < 2; ++j) {
            int t = t0 + wc * 32 + j * 16 + ccol;
            __half hv[4];
            hv[0] = __float2half(acc[i][j][0]);
            hv[1] = __float2half(acc[i][j][1]);
            hv[2] = __float2half(acc[i][j][2]);
            hv[3] = __float2half(acc[i][j][3]);
            *reinterpret_cast<short4*>(&eob[(size_t)t * NFFT + nb]) =
                *reinterpret_cast<short4*>(hv);
        }
    }
}

// ---------------- gather: window * butterfly * OLA / env -> out ----------------
__global__ void gather_kernel(const __half* __restrict__ EO,
                              const float* __restrict__ window,
                              float* __restrict__ out, int b0, int bcount) {
    int o = blockIdx.x * 256 + threadIdx.x;
    int s = o + PAD;
    int m = s >> 8, p = s & 255;
    float env = 1e-11f;
    float wv[4]; int tv[4]; int np[4]; float sg[4];
    #pragma unroll
    for (int j = 0; j < 4; ++j) {
        int t = m - j;
        bool ok = (t >= 0) && (t < T_);
        tv[j] = ok ? t : 0;
        np[j] = p + 256 * (j & 1);
        sg[j] = (j < 2) ? 1.f : -1.f;
        float ww = ok ? window[p + 256 * j] : 0.f;
        wv[j] = ww;
        env += ww * ww;
    }
    float inv = 1.0f / env;
    for (int bl = 0; bl < bcount; ++bl) {
        const __half* eo = EO + (size_t)bl * EO_E;
        float y = 0.f;
        #pragma unroll
        for (int j = 0; j < 4; ++j) {
            const __half* row = eo + (size_t)tv[j] * NFFT;
            float e = __half2float(row[np[j]]);
            float od = __half2float(row[512 + np[j]]);
            y = fmaf(wv[j], fmaf(sg[j], od, e), y);
        }
        out[(size_t)(b0 + bl) * OUTB + o] = y * inv;
    }
}

// ---------------- launch ----------------
extern "C" void kernel_launch(void* const* d_in, const int* in_sizes, int n_in,
                              void* d_out, int out_size, void* d_ws, size_t ws_size,
                              hipStream_t stream) {
    const float* x      = (const float*)d_in[0];
    const float* W      = (const float*)d_in[1];
    const float* bias   = (const float*)d_in[2];
    const float* window = (const float*)d_in[3];
    float* out = (float*)d_out;

    const size_t Ae  = (size_t)NFFT * KE;        //   589,824
    const size_t We  = (size_t)NW * H_;          //   294,912

    // bcount: largest that fits. Layout: [A(2)|W(4)|spec hi E,O|EO(fp16)]
    // xh (bf16, bcount*T_*H_ ushorts = bcount*4MB) aliases EO (bcount*8.4MB) -- xh dead
    // once gemm_a finishes, before gemm_eo writes EO (stream-ordered). Validated r12.
    int bcount = B_;
    for (;;) {
        size_t need = (2 * Ae + 4 * We + 2 * (size_t)bcount * SE_E) * sizeof(ushort)
                    + (size_t)bcount * EO_E * sizeof(__half);
        if (need <= ws_size || bcount == 1) break;
        bcount >>= 1;
    }

    ushort* Abh = (ushort*)d_ws;
    ushort* Abl = Abh + Ae;
    ushort* Wmh = Abl + Ae;
    ushort* Wml = Wmh + We;
    ushort* Wph = Wml + We;
    ushort* Wpl = Wph + We;
    ushort* SEh = Wpl + We;
    ushort* SOh = SEh + (size_t)bcount * SE_E;
    __half* EO  = (__half*)(SOh + (size_t)bcount * SE_E);
    ushort* xhb = (ushort*)EO;                     // alias: xh lives in EO region

    basis_kernel<<<(NFFT * KE) / 256, 256, 0, stream>>>(Abh, Abl);
    prepw_kernel<<<(NW * H_ + 255) / 256, 256, 0, stream>>>(W, Wmh, Wml, Wph, Wpl);

    for (int b0 = 0; b0 < B_; b0 += bcount) {
        convx_kernel<<<(int)((size_t)bcount * T_ * H_ / 8 / 256), 256, 0, stream>>>(x, xhb, b0);
        dim3 ga(bcount * 288);
        gemm_a_mfma<<<ga, 256, 0, stream>>>(xhb, Wmh, Wml, Wph, Wpl, bias, SEh, SOh);
        dim3 ge(512, bcount);
        gemm_eo_mfma<<<ge, 256, 0, stream>>>(Abh, Abl, SEh, SOh, EO);
        gather_kernel<<<OUTB / 256, 256, 0, stream>>>(EO, window, out, b0, bcount);
    }
}

// Round 15
// 248.099 us; speedup vs baseline: 1.2814x; 1.0474x over previous
//
#include <hip/hip_runtime.h>
#include <hip/hip_fp16.h>
#include <math.h>

#define B_  8
#define T_  4096
#define H_  512
#define FREQ 513
#define NW  576            // padded f (9 tiles of 64)
#define KE  576            // spec K: interleaved [re,im], padded; 9 tiles of 64
#define KVALID 544         // columns >= 544 are zero in basis AND spec -> skip
#define NFFT 1024
#define HOP 256
#define PAD 384
#define OUTB 1048576
#define CLAMP_MAXV 100.0f
#define SE_E ((size_t)T_ * KE)     // spec elems per batch (hi only)
#define EO_E ((size_t)T_ * NFFT)   // EO elems per batch

typedef __attribute__((ext_vector_type(8))) short bf16x8;
typedef __attribute__((ext_vector_type(4))) float f32x4;

__device__ inline ushort f2bf(float v) {
    union { float f; unsigned u; } x; x.f = v;
    unsigned r = x.u + 0x7FFFu + ((x.u >> 16) & 1u);   // RNE
    return (ushort)(r >> 16);
}
__device__ inline float bf2f(ushort h) {
    union { unsigned u; float f; } x; x.u = ((unsigned)h) << 16;
    return x.f;
}

#define GLOAD_LDS16(g, l) __builtin_amdgcn_global_load_lds( \
    (const __attribute__((address_space(1))) unsigned int*)(g), \
    (__attribute__((address_space(3))) unsigned int*)(l), 16, 0, 0)

// ---------------- basis: Ab[r][c]; r<512: E half (k=2kk), r>=512: O half (k=2kk+1) ----------------
__global__ void basis_kernel(ushort* __restrict__ Abh, ushort* __restrict__ Abl) {
    int idx = blockIdx.x * 256 + threadIdx.x;   // [0, 1024*576)
    int r = idx / KE, c = idx - r * KE;
    int np = (r < 512) ? r : (r - 512);
    int kk = c >> 1;
    int k = (r < 512) ? (2 * kk) : (2 * kk + 1);
    float v = 0.f;
    bool valid = (r < 512) ? (kk <= 256) : (kk <= 255);
    if (valid) {
        int m = (np * k) & (NFFT - 1);
        float a = (float)m * 6.135923151542565e-3f;       // 2*pi/1024
        float sc = ((k == 0) || (k == 512)) ? (1.0f / NFFT) : (2.0f / NFFT);
        v = ((c & 1) ? -sinf(a) : cosf(a)) * sc;
    }
    ushort h = f2bf(v);
    Abh[idx] = h;
    Abl[idx] = f2bf(v - bf2f(h));
}

// ---------------- W prep: Wm/Wp [f(576)][k(512)] hi/lo bf16 ----------------
__global__ void prepw_kernel(const float* __restrict__ W,
                             ushort* __restrict__ Wmh, ushort* __restrict__ Wml,
                             ushort* __restrict__ Wph, ushort* __restrict__ Wpl) {
    int idx = blockIdx.x * 256 + threadIdx.x;
    if (idx >= NW * H_) return;
    int k = idx / NW, f = idx - k * NW;
    float vm = 0.f, vp = 0.f;
    if (f < FREQ) {
        vm = W[(size_t)k * (2 * FREQ) + f];
        vp = W[(size_t)k * (2 * FREQ) + FREQ + f];
    }
    size_t dst = (size_t)f * H_ + k;
    ushort h1 = f2bf(vm); Wmh[dst] = h1; Wml[dst] = f2bf(vm - bf2f(h1));
    ushort h2 = f2bf(vp); Wph[dst] = h2; Wpl[dst] = f2bf(vp - bf2f(h2));
}

// ---------------- x conversion (hi only, per bcount-chunk): fp32 -> bf16 ----------------
__global__ void convx_kernel(const float* __restrict__ x, ushort* __restrict__ xh, int b0) {
    size_t i8 = ((size_t)blockIdx.x * 256 + threadIdx.x) * 8;
    const float* xp = x + (size_t)b0 * T_ * H_ + i8;
    float4 v0 = *reinterpret_cast<const float4*>(xp);
    float4 v1 = *reinterpret_cast<const float4*>(xp + 4);
    float xv[8];
    *reinterpret_cast<float4*>(&xv[0]) = v0;
    *reinterpret_cast<float4*>(&xv[4]) = v1;
    bf16x8 h;
    #pragma unroll
    for (int e = 0; e < 8; ++e) h[e] = (short)f2bf(xv[e]);
    *reinterpret_cast<bf16x8*>(xh + i8) = h;
}

// ---------------- GEMM A (MFMA): h = xh@(Wh+Wl) + b, tile 128t x 64f, K=512 ----------------
// grid: 1D bcount*288, XCD-swizzled (f fastest within an XCD slot run).
__global__ __launch_bounds__(256) void gemm_a_mfma(
    const ushort* __restrict__ xh,
    const ushort* __restrict__ Wmh, const ushort* __restrict__ Wml,
    const ushort* __restrict__ Wph, const ushort* __restrict__ Wpl,
    const float* __restrict__ bias,
    ushort* __restrict__ SEh, ushort* __restrict__ SOh)
{
    __shared__ __attribute__((aligned(16))) ushort SH[12288];

    const int tid = threadIdx.x;
    const int lane = tid & 63;
    const int w = tid >> 6;
    const int wr = w >> 1, wc = w & 1;

    const int nwg = gridDim.x;                 // bcount*288, % 8 == 0
    const int wg = blockIdx.x;
    const int gwi = (wg & 7) * (nwg >> 3) + (wg >> 3);
    const int m0 = (gwi / 9) * 128;            // chunk-local t row base
    const int f0 = (gwi % 9) * 64;

    const int srow = tid >> 2;           // 0..63
    const int ssel = ((tid & 3) ^ ((tid >> 3) & 3)) * 8;
    const int arow = lane & 15;
    const int kch  = (((lane >> 4) ^ ((arow >> 1) & 3))) * 8;
    const int xcol = (tid & 3) * 8;

    f32x4 accM[4][2] = {};
    f32x4 accP[4][2] = {};

    char* pSH = (char*)SH;

    for (int k0 = 0; k0 < H_; k0 += 32) {
        bf16x8 xv[2];
        #pragma unroll
        for (int q = 0; q < 2; ++q)
            xv[q] = *reinterpret_cast<const bf16x8*>(
                &xh[(size_t)(m0 + q * 64 + srow) * H_ + k0 + xcol]);
        size_t wo = (size_t)(f0 + srow) * H_ + k0 + ssel;
        GLOAD_LDS16(Wmh + wo, pSH + 8192  + w * 1024);
        GLOAD_LDS16(Wml + wo, pSH + 12288 + w * 1024);
        GLOAD_LDS16(Wph + wo, pSH + 16384 + w * 1024);
        GLOAD_LDS16(Wpl + wo, pSH + 20480 + w * 1024);
        #pragma unroll
        for (int q = 0; q < 2; ++q)
            *reinterpret_cast<bf16x8*>(&SH[(q * 64 + srow) * 32 + ssel]) = xv[q];
        __syncthreads();
        bf16x8 ah[4], bmh[2], bml[2], bph[2], bpl[2];
        #pragma unroll
        for (int i = 0; i < 4; ++i) {
            int r = (wr * 64 + i * 16 + arow) * 32 + kch;
            ah[i] = *reinterpret_cast<const bf16x8*>(&SH[r]);
        }
        #pragma unroll
        for (int j = 0; j < 2; ++j) {
            int r = (wc * 32 + j * 16 + arow) * 32 + kch;
            bmh[j] = *reinterpret_cast<const bf16x8*>(&SH[4096 + r]);
            bml[j] = *reinterpret_cast<const bf16x8*>(&SH[6144 + r]);
            bph[j] = *reinterpret_cast<const bf16x8*>(&SH[8192 + r]);
            bpl[j] = *reinterpret_cast<const bf16x8*>(&SH[10240 + r]);
        }
        #pragma unroll
        for (int i = 0; i < 4; ++i)
            #pragma unroll
            for (int j = 0; j < 2; ++j) {
                accM[i][j] = __builtin_amdgcn_mfma_f32_16x16x32_bf16(ah[i], bmh[j], accM[i][j], 0, 0, 0);
                accM[i][j] = __builtin_amdgcn_mfma_f32_16x16x32_bf16(ah[i], bml[j], accM[i][j], 0, 0, 0);
                accP[i][j] = __builtin_amdgcn_mfma_f32_16x16x32_bf16(ah[i], bph[j], accP[i][j], 0, 0, 0);
                accP[i][j] = __builtin_amdgcn_mfma_f32_16x16x32_bf16(ah[i], bpl[j], accP[i][j], 0, 0, 0);
            }
        __syncthreads();
    }

    // ---- epilogue: nonlinearity in place, then 2-pass (SE, SO) LDS transpose ----
    const int ccol = lane & 15;
    const int rbase = (lane >> 4) * 4;
    const int b_local = m0 >> 12;
    const int t00blk = m0 & (T_ - 1);
    const size_t specoff = (size_t)b_local * SE_E;
    const size_t tilebase = (size_t)(f0 >> 6) * T_ * 64;

    #pragma unroll
    for (int j = 0; j < 2; ++j) {
        int f = f0 + wc * 32 + j * 16 + ccol;
        bool live = (f < FREQ);
        float bm = live ? bias[f] : 0.f;
        float bp = live ? bias[FREQ + f] : 0.f;
        #pragma unroll
        for (int i = 0; i < 4; ++i)
            #pragma unroll
            for (int r = 0; r < 4; ++r) {
                float re = 0.f, im = 0.f;
                if (live) {
                    float mag = fminf(__expf(accM[i][j][r] + bm), CLAMP_MAXV);
                    float phv = accP[i][j][r] + bp;
                    float sp, cp; __sincosf(phv, &sp, &cp);
                    re = mag * cp; im = mag * sp;
                }
                accM[i][j][r] = re; accP[i][j][r] = im;
            }
    }

    const int par_mine = ccol & 1;
    const int row0 = tid >> 3;           // 0..31
    const int c8 = (tid & 7) * 8;
    #pragma unroll
    for (int pass = 0; pass < 2; ++pass) {
        if (par_mine == pass) {
            #pragma unroll
            for (int j = 0; j < 2; ++j) {
                int u = wc * 32 + j * 16 + ccol;
                int kl = u & ~1;
                #pragma unroll
                for (int i = 0; i < 4; ++i) {
                    #pragma unroll
                    for (int r = 0; r < 4; ++r) {
                        int tl = wr * 64 + i * 16 + rbase + r;
                        *reinterpret_cast<ushort2*>(&SH[tl * 72 + kl]) =
                            make_ushort2(f2bf(accM[i][j][r]), f2bf(accP[i][j][r]));
                    }
                }
            }
        }
        __syncthreads();
        ushort* d = (pass ? SOh : SEh) + specoff + tilebase;
        #pragma unroll
        for (int q2 = 0; q2 < 4; ++q2) {
            int row = q2 * 32 + row0;
            bf16x8 v = *reinterpret_cast<const bf16x8*>(&SH[row * 72 + c8]);
            *reinterpret_cast<bf16x8*>(&d[(size_t)(t00blk + row) * 64 + c8]) = v;
        }
        if (pass == 0) __syncthreads();
    }
}

// ---------------- stage 1 GEMM (MFMA, 2-term): EO[b][t][n''] = (Ah+Al).spec_hi, fp16 out -------
// grid: (256, bcount), XCD-swizzled (n fastest, t contiguous per XCD). Tile 128n x 128t.
// 32 MFMA per barrier pair; K trimmed to 544 (cols 544..575 structurally zero).
__global__ __launch_bounds__(256) void gemm_eo_mfma(
    const ushort* __restrict__ Abh, const ushort* __restrict__ Abl,
    const ushort* __restrict__ SEh, const ushort* __restrict__ SOh,
    __half* __restrict__ EO)
{
    __shared__ __attribute__((aligned(16))) ushort sAh[128 * 32];
    __shared__ __attribute__((aligned(16))) ushort sAl[128 * 32];
    __shared__ __attribute__((aligned(16))) ushort sBh[128 * 32];
    const int tid = threadIdx.x;
    const int lane = tid & 63;
    const int w = tid >> 6;
    const int wr = w >> 1, wc = w & 1;

    const int wg = blockIdx.x;                 // 256 = 32t x 8n, % 8 == 0
    const int gwi = (wg & 7) * 32 + (wg >> 3);
    const int t0 = (gwi >> 3) * 128;           // contiguous t per XCD
    const int n0 = (gwi & 7) * 128;            // n fastest
    const int b_local = blockIdx.y;

    const ushort* Bsh = ((n0 < 512) ? SEh : SOh) + (size_t)b_local * SE_E;

    const int srow = tid >> 2;
    const int ssel = ((tid & 3) ^ ((tid >> 3) & 3)) * 8;
    const int arow = lane & 15;
    const int kch  = (((lane >> 4) ^ ((arow >> 1) & 3))) * 8;

    f32x4 acc[4][4] = {};
    char* pAh = (char*)sAh; char* pAl = (char*)sAl;
    char* pBh = (char*)sBh;

    for (int k0 = 0; k0 < KVALID; k0 += 32) {
        #pragma unroll
        for (int q = 0; q < 2; ++q) {
            size_t ao = (size_t)(n0 + q * 64 + srow) * KE + k0 + ssel;
            GLOAD_LDS16(Abh + ao, pAh + q * 4096 + w * 1024);
            GLOAD_LDS16(Abl + ao, pAl + q * 4096 + w * 1024);
            size_t bo = ((size_t)(k0 >> 6) * T_ + t0 + q * 64 + srow) * 64 + (k0 & 32) + ssel;
            GLOAD_LDS16(Bsh + bo, pBh + q * 4096 + w * 1024);
        }
        __syncthreads();
        bf16x8 ah[4], al[4], bh[4];
        #pragma unroll
        for (int i = 0; i < 4; ++i) {
            int r = (wr * 64 + i * 16 + arow) * 32 + kch;
            ah[i] = *reinterpret_cast<const bf16x8*>(&sAh[r]);
            al[i] = *reinterpret_cast<const bf16x8*>(&sAl[r]);
        }
        #pragma unroll
        for (int j = 0; j < 4; ++j) {
            int r = (wc * 64 + j * 16 + arow) * 32 + kch;
            bh[j] = *reinterpret_cast<const bf16x8*>(&sBh[r]);
        }
        #pragma unroll
        for (int i = 0; i < 4; ++i)
            #pragma unroll
            for (int j = 0; j < 4; ++j) {
                acc[i][j] = __builtin_amdgcn_mfma_f32_16x16x32_bf16(ah[i], bh[j], acc[i][j], 0, 0, 0);
                acc[i][j] = __builtin_amdgcn_mfma_f32_16x16x32_bf16(al[i], bh[j], acc[i][j], 0, 0, 0);
            }
        __syncthreads();
    }

    // epilogue: C row = n'', col = t; EO[b][t][n''] as fp16, 8B stores
    const int ccol = lane & 15;
    const int rbase = (lane >> 4) * 4;
    __half* eob = EO + (size_t)b_local * EO_E;
    #pragma unroll
    for (int i = 0; i < 4; ++i) {
        int nb = n0 + wr * 64 + i * 16 + rbase;
        #pragma unroll
        for (int j = 0; j < 4; ++j) {
            int t = t0 + wc * 64 + j * 16 + ccol;
            __half hv[4];
            hv[0] = __float2half(acc[i][j][0]);
            hv[1] = __float2half(acc[i][j][1]);
            hv[2] = __float2half(acc[i][j][2]);
            hv[3] = __float2half(acc[i][j][3]);
            *reinterpret_cast<short4*>(&eob[(size_t)t * NFFT + nb]) =
                *reinterpret_cast<short4*>(hv);
        }
    }
}

// ---------------- gather: window * butterfly * OLA / env -> out ----------------
__global__ void gather_kernel(const __half* __restrict__ EO,
                              const float* __restrict__ window,
                              float* __restrict__ out, int b0, int bcount) {
    int o = blockIdx.x * 256 + threadIdx.x;
    int s = o + PAD;
    int m = s >> 8, p = s & 255;
    float env = 1e-11f;
    float wv[4]; int tv[4]; int np[4]; float sg[4];
    #pragma unroll
    for (int j = 0; j < 4; ++j) {
        int t = m - j;
        bool ok = (t >= 0) && (t < T_);
        tv[j] = ok ? t : 0;
        np[j] = p + 256 * (j & 1);
        sg[j] = (j < 2) ? 1.f : -1.f;
        float ww = ok ? window[p + 256 * j] : 0.f;
        wv[j] = ww;
        env += ww * ww;
    }
    float inv = 1.0f / env;
    for (int bl = 0; bl < bcount; ++bl) {
        const __half* eo = EO + (size_t)bl * EO_E;
        float y = 0.f;
        #pragma unroll
        for (int j = 0; j < 4; ++j) {
            const __half* row = eo + (size_t)tv[j] * NFFT;
            float e = __half2float(row[np[j]]);
            float od = __half2float(row[512 + np[j]]);
            y = fmaf(wv[j], fmaf(sg[j], od, e), y);
        }
        out[(size_t)(b0 + bl) * OUTB + o] = y * inv;
    }
}

// ---------------- launch ----------------
extern "C" void kernel_launch(void* const* d_in, const int* in_sizes, int n_in,
                              void* d_out, int out_size, void* d_ws, size_t ws_size,
                              hipStream_t stream) {
    const float* x      = (const float*)d_in[0];
    const float* W      = (const float*)d_in[1];
    const float* bias   = (const float*)d_in[2];
    const float* window = (const float*)d_in[3];
    float* out = (float*)d_out;

    const size_t Ae  = (size_t)NFFT * KE;        //   589,824
    const size_t We  = (size_t)NW * H_;          //   294,912

    // Layout: [A(2)|W(4)|spec hi E,O|EO(fp16)] ; xh aliases EO (validated r12/r14).
    int bcount = B_;
    for (;;) {
        size_t need = (2 * Ae + 4 * We + 2 * (size_t)bcount * SE_E) * sizeof(ushort)
                    + (size_t)bcount * EO_E * sizeof(__half);
        if (need <= ws_size || bcount == 1) break;
        bcount >>= 1;
    }

    ushort* Abh = (ushort*)d_ws;
    ushort* Abl = Abh + Ae;
    ushort* Wmh = Abl + Ae;
    ushort* Wml = Wmh + We;
    ushort* Wph = Wml + We;
    ushort* Wpl = Wph + We;
    ushort* SEh = Wpl + We;
    ushort* SOh = SEh + (size_t)bcount * SE_E;
    __half* EO  = (__half*)(SOh + (size_t)bcount * SE_E);
    ushort* xhb = (ushort*)EO;                     // alias: xh lives in EO region

    basis_kernel<<<(NFFT * KE) / 256, 256, 0, stream>>>(Abh, Abl);
    prepw_kernel<<<(NW * H_ + 255) / 256, 256, 0, stream>>>(W, Wmh, Wml, Wph, Wpl);

    for (int b0 = 0; b0 < B_; b0 += bcount) {
        convx_kernel<<<(int)((size_t)bcount * T_ * H_ / 8 / 256), 256, 0, stream>>>(x, xhb, b0);
        dim3 ga(bcount * 288);
        gemm_a_mfma<<<ga, 256, 0, stream>>>(xhb, Wmh, Wml, Wph, Wpl, bias, SEh, SOh);
        dim3 ge(256, bcount);
        gemm_eo_mfma<<<ge, 256, 0, stream>>>(Abh, Abl, SEh, SOh, EO);
        gather_kernel<<<OUTB / 256, 256, 0, stream>>>(EO, window, out, b0, bcount);
    }
}

// Round 16
// 179.260 us; speedup vs baseline: 1.7734x; 1.3840x over previous
//
#include <hip/hip_runtime.h>
#include <hip/hip_fp16.h>
#include <math.h>

#define B_  8
#define T_  4096
#define H_  512
#define FREQ 513
#define NW  576            // padded f (9 tiles of 64)
#define KE  576            // spec K: interleaved [re,im], padded; 9 tiles of 64
#define NFFT 1024
#define HOP 256
#define PAD 384
#define OUTB 1048576
#define CLAMP_MAXV 100.0f
#define SE_E ((size_t)T_ * KE)     // spec elems per batch (fp16)
#define EO_E ((size_t)T_ * NFFT)   // EO elems per batch

typedef __attribute__((ext_vector_type(8))) _Float16 f16x8;
typedef __attribute__((ext_vector_type(4))) float f32x4;

__device__ inline ushort f2h(float v) {
    _Float16 h = (_Float16)v;
    ushort u; __builtin_memcpy(&u, &h, 2); return u;
}

#define GLOAD_LDS16(g, l) __builtin_amdgcn_global_load_lds( \
    (const __attribute__((address_space(1))) unsigned int*)(g), \
    (__attribute__((address_space(3))) unsigned int*)(l), 16, 0, 0)

// ---------------- basis (fp16): Ab[r][c]; r<512: E half (k=2kk), r>=512: O half (k=2kk+1) --------
__global__ void basis_kernel(ushort* __restrict__ Ab) {
    int idx = blockIdx.x * 256 + threadIdx.x;   // [0, 1024*576)
    int r = idx / KE, c = idx - r * KE;
    int np = (r < 512) ? r : (r - 512);
    int kk = c >> 1;
    int k = (r < 512) ? (2 * kk) : (2 * kk + 1);
    float v = 0.f;
    bool valid = (r < 512) ? (kk <= 256) : (kk <= 255);
    if (valid) {
        int m = (np * k) & (NFFT - 1);
        float a = (float)m * 6.135923151542565e-3f;       // 2*pi/1024
        float sc = ((k == 0) || (k == 512)) ? (1.0f / NFFT) : (2.0f / NFFT);
        v = ((c & 1) ? -sinf(a) : cosf(a)) * sc;
    }
    Ab[idx] = f2h(v);
}

// ---------------- W prep (fp16): Wm/Wp [f(576)][k(512)] ----------------
__global__ void prepw_kernel(const float* __restrict__ W,
                             ushort* __restrict__ Wm, ushort* __restrict__ Wp) {
    int idx = blockIdx.x * 256 + threadIdx.x;
    if (idx >= NW * H_) return;
    int k = idx / NW, f = idx - k * NW;
    float vm = 0.f, vp = 0.f;
    if (f < FREQ) {
        vm = W[(size_t)k * (2 * FREQ) + f];
        vp = W[(size_t)k * (2 * FREQ) + FREQ + f];
    }
    size_t dst = (size_t)f * H_ + k;
    Wm[dst] = f2h(vm);
    Wp[dst] = f2h(vp);
}

// ---------------- x conversion (fp16, per bcount-chunk) ----------------
__global__ void convx_kernel(const float* __restrict__ x, ushort* __restrict__ xh, int b0) {
    size_t i8 = ((size_t)blockIdx.x * 256 + threadIdx.x) * 8;
    const float* xp = x + (size_t)b0 * T_ * H_ + i8;
    float4 v0 = *reinterpret_cast<const float4*>(xp);
    float4 v1 = *reinterpret_cast<const float4*>(xp + 4);
    float xv[8];
    *reinterpret_cast<float4*>(&xv[0]) = v0;
    *reinterpret_cast<float4*>(&xv[4]) = v1;
    ushort h[8];
    #pragma unroll
    for (int e = 0; e < 8; ++e) h[e] = f2h(xv[e]);
    *reinterpret_cast<ushort4*>(xh + i8)     = make_ushort4(h[0], h[1], h[2], h[3]);
    *reinterpret_cast<ushort4*>(xh + i8 + 4) = make_ushort4(h[4], h[5], h[6], h[7]);
}

// ---------------- GEMM A (fp16 MFMA): h = x@W + b, tile 128t x 64f, BK=64 ----------------
// grid: 1D bcount*288, XCD-swizzled (f fastest). LDS 32KB. 32 MFMA / 8 gloads per barrier.
__global__ __launch_bounds__(256) void gemm_a_mfma(
    const ushort* __restrict__ xh,
    const ushort* __restrict__ Wm, const ushort* __restrict__ Wp,
    const float* __restrict__ bias,
    ushort* __restrict__ SEh, ushort* __restrict__ SOh)
{
    // ushort idx: X @0 [128*64], Wm @8192 [64*64], Wp @12288 [64*64] = 16384 (32KB)
    // epilogue reuses [0, 9216) per pass
    __shared__ __attribute__((aligned(16))) ushort SH[16384];

    const int tid = threadIdx.x;
    const int lane = tid & 63;
    const int w = tid >> 6;
    const int wr = w >> 1, wc = w & 1;
    const int g = lane >> 4;

    const int nwg = gridDim.x;                 // bcount*288, % 8 == 0
    const int wg = blockIdx.x;
    const int gwi = (wg & 7) * (nwg >> 3) + (wg >> 3);
    const int m0 = (gwi / 9) * 128;            // chunk-local t row base
    const int f0 = (gwi % 9) * 64;

    const int srow8 = tid >> 3;                // 0..31
    const int csrc = (((tid & 7) ^ ((tid >> 3) & 7))) * 8;   // source chunk (elems)
    const int arow = lane & 15;

    f32x4 accM[4][2] = {};
    f32x4 accP[4][2] = {};

    char* pSH = (char*)SH;

    for (int k0 = 0; k0 < H_; k0 += 64) {
        #pragma unroll
        for (int q = 0; q < 4; ++q) {
            size_t xo = (size_t)(m0 + q * 32 + srow8) * H_ + k0 + csrc;
            GLOAD_LDS16(xh + xo, pSH + q * 4096 + w * 1024);
        }
        #pragma unroll
        for (int q = 0; q < 2; ++q) {
            size_t wo = (size_t)(f0 + q * 32 + srow8) * H_ + k0 + csrc;
            GLOAD_LDS16(Wm + wo, pSH + 16384 + q * 4096 + w * 1024);
            GLOAD_LDS16(Wp + wo, pSH + 24576 + q * 4096 + w * 1024);
        }
        __syncthreads();
        #pragma unroll
        for (int kh = 0; kh < 2; ++kh) {
            f16x8 ax[4], wm[2], wp[2];
            #pragma unroll
            for (int i = 0; i < 4; ++i) {
                int row = wr * 64 + i * 16 + arow;
                int cc = (kh * 4 + g) ^ (row & 7);
                ax[i] = *reinterpret_cast<const f16x8*>(&SH[row * 64 + cc * 8]);
            }
            #pragma unroll
            for (int j = 0; j < 2; ++j) {
                int row = wc * 32 + j * 16 + arow;
                int cc = (kh * 4 + g) ^ (row & 7);
                wm[j] = *reinterpret_cast<const f16x8*>(&SH[8192 + row * 64 + cc * 8]);
                wp[j] = *reinterpret_cast<const f16x8*>(&SH[12288 + row * 64 + cc * 8]);
            }
            #pragma unroll
            for (int i = 0; i < 4; ++i)
                #pragma unroll
                for (int j = 0; j < 2; ++j) {
                    accM[i][j] = __builtin_amdgcn_mfma_f32_16x16x32_f16(ax[i], wm[j], accM[i][j], 0, 0, 0);
                    accP[i][j] = __builtin_amdgcn_mfma_f32_16x16x32_f16(ax[i], wp[j], accP[i][j], 0, 0, 0);
                }
        }
        __syncthreads();
    }

    // ---- epilogue: nonlinearity in place, then 2-pass (SE, SO) LDS transpose ----
    const int ccol = lane & 15;
    const int rbase = (lane >> 4) * 4;
    const int b_local = m0 >> 12;
    const int t00blk = m0 & (T_ - 1);
    const size_t specoff = (size_t)b_local * SE_E;
    const size_t tilebase = (size_t)(f0 >> 6) * T_ * 64;

    #pragma unroll
    for (int j = 0; j < 2; ++j) {
        int f = f0 + wc * 32 + j * 16 + ccol;
        bool live = (f < FREQ);
        float bm = live ? bias[f] : 0.f;
        float bp = live ? bias[FREQ + f] : 0.f;
        #pragma unroll
        for (int i = 0; i < 4; ++i)
            #pragma unroll
            for (int r = 0; r < 4; ++r) {
                float re = 0.f, im = 0.f;
                if (live) {
                    float mag = fminf(__expf(accM[i][j][r] + bm), CLAMP_MAXV);
                    float phv = accP[i][j][r] + bp;
                    float sp, cp; __sincosf(phv, &sp, &cp);
                    re = mag * cp; im = mag * sp;
                }
                accM[i][j][r] = re; accP[i][j][r] = im;
            }
    }

    const int par_mine = ccol & 1;
    const int row0 = tid >> 3;           // 0..31
    const int c8 = (tid & 7) * 8;
    #pragma unroll
    for (int pass = 0; pass < 2; ++pass) {
        if (par_mine == pass) {
            #pragma unroll
            for (int j = 0; j < 2; ++j) {
                int u = wc * 32 + j * 16 + ccol;
                int kl = u & ~1;
                #pragma unroll
                for (int i = 0; i < 4; ++i) {
                    #pragma unroll
                    for (int r = 0; r < 4; ++r) {
                        int tl = wr * 64 + i * 16 + rbase + r;
                        *reinterpret_cast<ushort2*>(&SH[tl * 72 + kl]) =
                            make_ushort2(f2h(accM[i][j][r]), f2h(accP[i][j][r]));
                    }
                }
            }
        }
        __syncthreads();
        ushort* d = (pass ? SOh : SEh) + specoff + tilebase;
        #pragma unroll
        for (int q2 = 0; q2 < 4; ++q2) {
            int row = q2 * 32 + row0;
            ushort4 v0 = *reinterpret_cast<const ushort4*>(&SH[row * 72 + c8]);
            ushort4 v1 = *reinterpret_cast<const ushort4*>(&SH[row * 72 + c8 + 4]);
            ushort* dp = &d[(size_t)(t00blk + row) * 64 + c8];
            *reinterpret_cast<ushort4*>(dp) = v0;
            *reinterpret_cast<ushort4*>(dp + 4) = v1;
        }
        if (pass == 0) __syncthreads();
    }
}

// ---------------- stage 1 GEMM (fp16 MFMA, 1-term): EO[b][t][n''] = basis.spec ----------------
// grid: (256, bcount), XCD-swizzled. Tile 128n x 128t, BK=64; 32 MFMA / 8 gloads per barrier.
__global__ __launch_bounds__(256) void gemm_eo_mfma(
    const ushort* __restrict__ Ab,
    const ushort* __restrict__ SEh, const ushort* __restrict__ SOh,
    __half* __restrict__ EO)
{
    __shared__ __attribute__((aligned(16))) ushort sA[128 * 64];
    __shared__ __attribute__((aligned(16))) ushort sB[128 * 64];
    const int tid = threadIdx.x;
    const int lane = tid & 63;
    const int w = tid >> 6;
    const int wr = w >> 1, wc = w & 1;
    const int g = lane >> 4;

    const int wg = blockIdx.x;                 // 256 = 32t x 8n, % 8 == 0
    const int gwi = (wg & 7) * 32 + (wg >> 3);
    const int t0 = (gwi >> 3) * 128;           // contiguous t per XCD
    const int n0 = (gwi & 7) * 128;            // n fastest
    const int b_local = blockIdx.y;

    const ushort* Bsh = ((n0 < 512) ? SEh : SOh) + (size_t)b_local * SE_E;

    const int srow8 = tid >> 3;
    const int csrc = (((tid & 7) ^ ((tid >> 3) & 7))) * 8;
    const int arow = lane & 15;

    f32x4 acc[4][4] = {};
    char* pA = (char*)sA;
    char* pB = (char*)sB;

    for (int k0 = 0; k0 < KE; k0 += 64) {
        #pragma unroll
        for (int q = 0; q < 4; ++q) {
            size_t ao = (size_t)(n0 + q * 32 + srow8) * KE + k0 + csrc;
            GLOAD_LDS16(Ab + ao, pA + q * 4096 + w * 1024);
            size_t bo = ((size_t)(k0 >> 6) * T_ + t0 + q * 32 + srow8) * 64 + csrc;
            GLOAD_LDS16(Bsh + bo, pB + q * 4096 + w * 1024);
        }
        __syncthreads();
        #pragma unroll
        for (int kh = 0; kh < 2; ++kh) {
            f16x8 a[4], b[4];
            #pragma unroll
            for (int i = 0; i < 4; ++i) {
                int row = wr * 64 + i * 16 + arow;
                int cc = (kh * 4 + g) ^ (row & 7);
                a[i] = *reinterpret_cast<const f16x8*>(&sA[row * 64 + cc * 8]);
            }
            #pragma unroll
            for (int j = 0; j < 4; ++j) {
                int row = wc * 64 + j * 16 + arow;
                int cc = (kh * 4 + g) ^ (row & 7);
                b[j] = *reinterpret_cast<const f16x8*>(&sB[row * 64 + cc * 8]);
            }
            #pragma unroll
            for (int i = 0; i < 4; ++i)
                #pragma unroll
                for (int j = 0; j < 4; ++j)
                    acc[i][j] = __builtin_amdgcn_mfma_f32_16x16x32_f16(a[i], b[j], acc[i][j], 0, 0, 0);
        }
        __syncthreads();
    }

    // epilogue: C row = n'', col = t; EO[b][t][n''] as fp16, 8B stores
    const int ccol = lane & 15;
    const int rbase = (lane >> 4) * 4;
    __half* eob = EO + (size_t)b_local * EO_E;
    #pragma unroll
    for (int i = 0; i < 4; ++i) {
        int nb = n0 + wr * 64 + i * 16 + rbase;
        #pragma unroll
        for (int j = 0; j < 4; ++j) {
            int t = t0 + wc * 64 + j * 16 + ccol;
            __half hv[4];
            hv[0] = __float2half(acc[i][j][0]);
            hv[1] = __float2half(acc[i][j][1]);
            hv[2] = __float2half(acc[i][j][2]);
            hv[3] = __float2half(acc[i][j][3]);
            *reinterpret_cast<short4*>(&eob[(size_t)t * NFFT + nb]) =
                *reinterpret_cast<short4*>(hv);
        }
    }
}

// ---------------- gather: window * butterfly * OLA / env -> out ----------------
__global__ void gather_kernel(const __half* __restrict__ EO,
                              const float* __restrict__ window,
                              float* __restrict__ out, int b0, int bcount) {
    int o = blockIdx.x * 256 + threadIdx.x;
    int s = o + PAD;
    int m = s >> 8, p = s & 255;
    float env = 1e-11f;
    float wv[4]; int tv[4]; int np[4]; float sg[4];
    #pragma unroll
    for (int j = 0; j < 4; ++j) {
        int t = m - j;
        bool ok = (t >= 0) && (t < T_);
        tv[j] = ok ? t : 0;
        np[j] = p + 256 * (j & 1);
        sg[j] = (j < 2) ? 1.f : -1.f;
        float ww = ok ? window[p + 256 * j] : 0.f;
        wv[j] = ww;
        env += ww * ww;
    }
    float inv = 1.0f / env;
    for (int bl = 0; bl < bcount; ++bl) {
        const __half* eo = EO + (size_t)bl * EO_E;
        float y = 0.f;
        #pragma unroll
        for (int j = 0; j < 4; ++j) {
            const __half* row = eo + (size_t)tv[j] * NFFT;
            float e = __half2float(row[np[j]]);
            float od = __half2float(row[512 + np[j]]);
            y = fmaf(wv[j], fmaf(sg[j], od, e), y);
        }
        out[(size_t)(b0 + bl) * OUTB + o] = y * inv;
    }
}

// ---------------- launch ----------------
extern "C" void kernel_launch(void* const* d_in, const int* in_sizes, int n_in,
                              void* d_out, int out_size, void* d_ws, size_t ws_size,
                              hipStream_t stream) {
    const float* x      = (const float*)d_in[0];
    const float* W      = (const float*)d_in[1];
    const float* bias   = (const float*)d_in[2];
    const float* window = (const float*)d_in[3];
    float* out = (float*)d_out;

    const size_t Ae  = (size_t)NFFT * KE;        //   589,824
    const size_t We  = (size_t)NW * H_;          //   294,912

    // Layout: [Ab|Wm|Wp|spec E,O (fp16)|EO(fp16)] ; xh (fp16) aliases EO (validated r12/r14).
    int bcount = B_;
    for (;;) {
        size_t need = (Ae + 2 * We + 2 * (size_t)bcount * SE_E) * sizeof(ushort)
                    + (size_t)bcount * EO_E * sizeof(__half);
        if (need <= ws_size || bcount == 1) break;
        bcount >>= 1;
    }

    ushort* Ab  = (ushort*)d_ws;
    ushort* Wm  = Ab + Ae;
    ushort* Wp  = Wm + We;
    ushort* SEh = Wp + We;
    ushort* SOh = SEh + (size_t)bcount * SE_E;
    __half* EO  = (__half*)(SOh + (size_t)bcount * SE_E);
    ushort* xhb = (ushort*)EO;                     // alias: xh lives in EO region

    basis_kernel<<<(NFFT * KE) / 256, 256, 0, stream>>>(Ab);
    prepw_kernel<<<(NW * H_ + 255) / 256, 256, 0, stream>>>(W, Wm, Wp);

    for (int b0 = 0; b0 < B_; b0 += bcount) {
        convx_kernel<<<(int)((size_t)bcount * T_ * H_ / 8 / 256), 256, 0, stream>>>(x, xhb, b0);
        dim3 ga(bcount * 288);
        gemm_a_mfma<<<ga, 256, 0, stream>>>(xhb, Wm, Wp, bias, SEh, SOh);
        dim3 ge(256, bcount);
        gemm_eo_mfma<<<ge, 256, 0, stream>>>(Ab, SEh, SOh, EO);
        gather_kernel<<<OUTB / 256, 256, 0, stream>>>(EO, window, out, b0, bcount);
    }
}

// Round 17
// 176.909 us; speedup vs baseline: 1.7970x; 1.0133x over previous
//
#include <hip/hip_runtime.h>
#include <hip/hip_fp16.h>
#include <math.h>

#define B_  8
#define T_  4096
#define H_  512
#define FREQ 513
#define NW  576            // padded f (9 tiles of 64)
#define KE  576            // spec K: interleaved [re,im], padded; 9 tiles of 64
#define NFFT 1024
#define HOP 256
#define PAD 384
#define OUTB 1048576
#define CLAMP_MAXV 100.0f
#define SE_E ((size_t)T_ * KE)     // spec elems per batch (fp16)
#define EO_E ((size_t)T_ * NFFT)   // EO elems per batch

typedef __attribute__((ext_vector_type(8))) _Float16 f16x8;
typedef __attribute__((ext_vector_type(4))) float f32x4;

__device__ inline ushort f2h(float v) {
    _Float16 h = (_Float16)v;
    ushort u; __builtin_memcpy(&u, &h, 2); return u;
}
__device__ inline float h2f(ushort u) {
    _Float16 h; __builtin_memcpy(&h, &u, 2); return (float)h;
}

#define GLOAD_LDS16(g, l) __builtin_amdgcn_global_load_lds( \
    (const __attribute__((address_space(1))) unsigned int*)(g), \
    (__attribute__((address_space(3))) unsigned int*)(l), 16, 0, 0)

// ---------------- basis (fp16): Ab[r][c]; r<512: E half (k=2kk), r>=512: O half (k=2kk+1) --------
__global__ void basis_kernel(ushort* __restrict__ Ab) {
    int idx = blockIdx.x * 256 + threadIdx.x;   // [0, 1024*576)
    int r = idx / KE, c = idx - r * KE;
    int np = (r < 512) ? r : (r - 512);
    int kk = c >> 1;
    int k = (r < 512) ? (2 * kk) : (2 * kk + 1);
    float v = 0.f;
    bool valid = (r < 512) ? (kk <= 256) : (kk <= 255);
    if (valid) {
        int m = (np * k) & (NFFT - 1);
        float a = (float)m * 6.135923151542565e-3f;       // 2*pi/1024
        float sc = ((k == 0) || (k == 512)) ? (1.0f / NFFT) : (2.0f / NFFT);
        v = ((c & 1) ? -sinf(a) : cosf(a)) * sc;
    }
    Ab[idx] = f2h(v);
}

// ---------------- W prep (fp16): Wm/Wp [f(576)][k(512)] ----------------
__global__ void prepw_kernel(const float* __restrict__ W,
                             ushort* __restrict__ Wm, ushort* __restrict__ Wp) {
    int idx = blockIdx.x * 256 + threadIdx.x;
    if (idx >= NW * H_) return;
    int k = idx / NW, f = idx - k * NW;
    float vm = 0.f, vp = 0.f;
    if (f < FREQ) {
        vm = W[(size_t)k * (2 * FREQ) + f];
        vp = W[(size_t)k * (2 * FREQ) + FREQ + f];
    }
    size_t dst = (size_t)f * H_ + k;
    Wm[dst] = f2h(vm);
    Wp[dst] = f2h(vp);
}

// ---------------- x conversion (fp16, per bcount-chunk) ----------------
__global__ void convx_kernel(const float* __restrict__ x, ushort* __restrict__ xh, int b0) {
    size_t i8 = ((size_t)blockIdx.x * 256 + threadIdx.x) * 8;
    const float* xp = x + (size_t)b0 * T_ * H_ + i8;
    float4 v0 = *reinterpret_cast<const float4*>(xp);
    float4 v1 = *reinterpret_cast<const float4*>(xp + 4);
    float xv[8];
    *reinterpret_cast<float4*>(&xv[0]) = v0;
    *reinterpret_cast<float4*>(&xv[4]) = v1;
    ushort h[8];
    #pragma unroll
    for (int e = 0; e < 8; ++e) h[e] = f2h(xv[e]);
    *reinterpret_cast<ushort4*>(xh + i8)     = make_ushort4(h[0], h[1], h[2], h[3]);
    *reinterpret_cast<ushort4*>(xh + i8 + 4) = make_ushort4(h[4], h[5], h[6], h[7]);
}

// ---------------- nyquist-ish column f=512: fp32 GEMV -> SE tile 8 ----------------
// grid: (T_/64, bcount); block 256 (4 lanes per t-row).
__global__ void nyq_kernel(const ushort* __restrict__ xh,
                           const ushort* __restrict__ Wm, const ushort* __restrict__ Wp,
                           const float* __restrict__ bias,
                           ushort* __restrict__ SEh) {
    __shared__ ushort sW[1024];          // [0,512): Wm row 512; [512,1024): Wp row 512
    const int tid = threadIdx.x;
    const int b_local = blockIdx.y;
    const int t0 = blockIdx.x * 64;

    if (tid < 128) {
        const ushort* src = ((tid < 64) ? &Wm[(size_t)512 * H_] : &Wp[(size_t)512 * H_]);
        int base = (tid < 64) ? 0 : 512;
        int i = (tid & 63) * 8;
        *reinterpret_cast<ushort4*>(&sW[base + i])     = *reinterpret_cast<const ushort4*>(&src[i]);
        *reinterpret_cast<ushort4*>(&sW[base + i + 4]) = *reinterpret_cast<const ushort4*>(&src[i + 4]);
    }
    __syncthreads();

    const int tl = tid >> 2;             // 0..63
    const int q = tid & 3;               // k-quarter
    const ushort* xr = xh + ((size_t)b_local * T_ + t0 + tl) * H_ + q * 128;
    float accm = 0.f, accp = 0.f;
    #pragma unroll
    for (int i = 0; i < 128; i += 8) {
        ushort4 xa = *reinterpret_cast<const ushort4*>(&xr[i]);
        ushort4 xb = *reinterpret_cast<const ushort4*>(&xr[i + 4]);
        ushort4 ma = *reinterpret_cast<const ushort4*>(&sW[q * 128 + i]);
        ushort4 mb = *reinterpret_cast<const ushort4*>(&sW[q * 128 + i + 4]);
        ushort4 pa = *reinterpret_cast<const ushort4*>(&sW[512 + q * 128 + i]);
        ushort4 pb = *reinterpret_cast<const ushort4*>(&sW[512 + q * 128 + i + 4]);
        ushort xs[8] = {xa.x, xa.y, xa.z, xa.w, xb.x, xb.y, xb.z, xb.w};
        ushort ms[8] = {ma.x, ma.y, ma.z, ma.w, mb.x, mb.y, mb.z, mb.w};
        ushort ps[8] = {pa.x, pa.y, pa.z, pa.w, pb.x, pb.y, pb.z, pb.w};
        #pragma unroll
        for (int e = 0; e < 8; ++e) {
            float xv = h2f(xs[e]);
            accm = fmaf(xv, h2f(ms[e]), accm);
            accp = fmaf(xv, h2f(ps[e]), accp);
        }
    }
    accm += __shfl_down(accm, 2); accm += __shfl_down(accm, 1);
    accp += __shfl_down(accp, 2); accp += __shfl_down(accp, 1);

    ushort vals[16] = {0};
    if (q == 0) {
        float mag = fminf(__expf(accm + bias[512]), CLAMP_MAXV);
        float phv = accp + bias[FREQ + 512];
        float sp, cp; __sincosf(phv, &sp, &cp);
        vals[0] = f2h(mag * cp);
        vals[1] = f2h(mag * sp);
    }
    ushort* drow = SEh + (size_t)b_local * SE_E + (size_t)8 * T_ * 64
                 + (size_t)(t0 + tl) * 64 + q * 16;
    *reinterpret_cast<ushort4*>(drow)      = make_ushort4(vals[0], vals[1], vals[2], vals[3]);
    *reinterpret_cast<ushort4*>(drow + 4)  = make_ushort4(vals[4], vals[5], vals[6], vals[7]);
    *reinterpret_cast<ushort4*>(drow + 8)  = make_ushort4(vals[8], vals[9], vals[10], vals[11]);
    *reinterpret_cast<ushort4*>(drow + 12) = make_ushort4(vals[12], vals[13], vals[14], vals[15]);
}

// ---------------- GEMM A (fp16 MFMA): h = x@W + b, tile 128t x 64f, BK=64, 8 live f-tiles ------
// grid: 1D bcount*256, XCD-swizzled (f fastest). LDS 32KB. 32 MFMA / 8 gloads per barrier.
__global__ __launch_bounds__(256) void gemm_a_mfma(
    const ushort* __restrict__ xh,
    const ushort* __restrict__ Wm, const ushort* __restrict__ Wp,
    const float* __restrict__ bias,
    ushort* __restrict__ SEh, ushort* __restrict__ SOh)
{
    __shared__ __attribute__((aligned(16))) ushort SH[16384];

    const int tid = threadIdx.x;
    const int lane = tid & 63;
    const int w = tid >> 6;
    const int wr = w >> 1, wc = w & 1;
    const int g = lane >> 4;

    const int nwg = gridDim.x;                 // bcount*256, % 8 == 0
    const int wg = blockIdx.x;
    const int gwi = (wg & 7) * (nwg >> 3) + (wg >> 3);
    const int m0 = (gwi >> 3) * 128;           // chunk-local t row base
    const int f0 = (gwi & 7) * 64;             // f fastest (tiles 0..7, all live)

    const int srow8 = tid >> 3;                // 0..31
    const int csrc = (((tid & 7) ^ ((tid >> 3) & 7))) * 8;
    const int arow = lane & 15;

    f32x4 accM[4][2] = {};
    f32x4 accP[4][2] = {};

    char* pSH = (char*)SH;

    for (int k0 = 0; k0 < H_; k0 += 64) {
        #pragma unroll
        for (int q = 0; q < 4; ++q) {
            size_t xo = (size_t)(m0 + q * 32 + srow8) * H_ + k0 + csrc;
            GLOAD_LDS16(xh + xo, pSH + q * 4096 + w * 1024);
        }
        #pragma unroll
        for (int q = 0; q < 2; ++q) {
            size_t wo = (size_t)(f0 + q * 32 + srow8) * H_ + k0 + csrc;
            GLOAD_LDS16(Wm + wo, pSH + 16384 + q * 4096 + w * 1024);
            GLOAD_LDS16(Wp + wo, pSH + 24576 + q * 4096 + w * 1024);
        }
        __syncthreads();
        #pragma unroll
        for (int kh = 0; kh < 2; ++kh) {
            f16x8 ax[4], wm[2], wp[2];
            #pragma unroll
            for (int i = 0; i < 4; ++i) {
                int row = wr * 64 + i * 16 + arow;
                int cc = (kh * 4 + g) ^ (row & 7);
                ax[i] = *reinterpret_cast<const f16x8*>(&SH[row * 64 + cc * 8]);
            }
            #pragma unroll
            for (int j = 0; j < 2; ++j) {
                int row = wc * 32 + j * 16 + arow;
                int cc = (kh * 4 + g) ^ (row & 7);
                wm[j] = *reinterpret_cast<const f16x8*>(&SH[8192 + row * 64 + cc * 8]);
                wp[j] = *reinterpret_cast<const f16x8*>(&SH[12288 + row * 64 + cc * 8]);
            }
            #pragma unroll
            for (int i = 0; i < 4; ++i)
                #pragma unroll
                for (int j = 0; j < 2; ++j) {
                    accM[i][j] = __builtin_amdgcn_mfma_f32_16x16x32_f16(ax[i], wm[j], accM[i][j], 0, 0, 0);
                    accP[i][j] = __builtin_amdgcn_mfma_f32_16x16x32_f16(ax[i], wp[j], accP[i][j], 0, 0, 0);
                }
        }
        __syncthreads();
    }

    // ---- epilogue: nonlinearity (all f live), then 2-pass (SE, SO) LDS transpose ----
    const int ccol = lane & 15;
    const int rbase = (lane >> 4) * 4;
    const int b_local = m0 >> 12;
    const int t00blk = m0 & (T_ - 1);
    const size_t specoff = (size_t)b_local * SE_E;
    const size_t tilebase = (size_t)(f0 >> 6) * T_ * 64;

    #pragma unroll
    for (int j = 0; j < 2; ++j) {
        int f = f0 + wc * 32 + j * 16 + ccol;      // <= 511, always live
        float bm = bias[f];
        float bp = bias[FREQ + f];
        #pragma unroll
        for (int i = 0; i < 4; ++i)
            #pragma unroll
            for (int r = 0; r < 4; ++r) {
                float mag = fminf(__expf(accM[i][j][r] + bm), CLAMP_MAXV);
                float phv = accP[i][j][r] + bp;
                float sp, cp; __sincosf(phv, &sp, &cp);
                accM[i][j][r] = mag * cp;
                accP[i][j][r] = mag * sp;
            }
    }

    const int par_mine = ccol & 1;
    const int row0 = tid >> 3;           // 0..31
    const int c8 = (tid & 7) * 8;
    #pragma unroll
    for (int pass = 0; pass < 2; ++pass) {
        if (par_mine == pass) {
            #pragma unroll
            for (int j = 0; j < 2; ++j) {
                int u = wc * 32 + j * 16 + ccol;
                int kl = u & ~1;
                #pragma unroll
                for (int i = 0; i < 4; ++i) {
                    #pragma unroll
                    for (int r = 0; r < 4; ++r) {
                        int tl = wr * 64 + i * 16 + rbase + r;
                        *reinterpret_cast<ushort2*>(&SH[tl * 72 + kl]) =
                            make_ushort2(f2h(accM[i][j][r]), f2h(accP[i][j][r]));
                    }
                }
            }
        }
        __syncthreads();
        ushort* d = (pass ? SOh : SEh) + specoff + tilebase;
        #pragma unroll
        for (int q2 = 0; q2 < 4; ++q2) {
            int row = q2 * 32 + row0;
            ushort4 v0 = *reinterpret_cast<const ushort4*>(&SH[row * 72 + c8]);
            ushort4 v1 = *reinterpret_cast<const ushort4*>(&SH[row * 72 + c8 + 4]);
            ushort* dp = &d[(size_t)(t00blk + row) * 64 + c8];
            *reinterpret_cast<ushort4*>(dp) = v0;
            *reinterpret_cast<ushort4*>(dp + 4) = v1;
        }
        if (pass == 0) __syncthreads();
    }
}

// ---------------- stage 1 GEMM (fp16 MFMA): EO[b][t][n''] = basis.spec ----------------
// grid: (256, bcount), XCD-swizzled. Tile 128n x 128t, BK=64. K: E-half 576, O-half 512.
__global__ __launch_bounds__(256) void gemm_eo_mfma(
    const ushort* __restrict__ Ab,
    const ushort* __restrict__ SEh, const ushort* __restrict__ SOh,
    __half* __restrict__ EO)
{
    __shared__ __attribute__((aligned(16))) ushort sA[128 * 64];
    __shared__ __attribute__((aligned(16))) ushort sB[128 * 64];
    const int tid = threadIdx.x;
    const int lane = tid & 63;
    const int w = tid >> 6;
    const int wr = w >> 1, wc = w & 1;
    const int g = lane >> 4;

    const int wg = blockIdx.x;                 // 256 = 32t x 8n, % 8 == 0
    const int gwi = (wg & 7) * 32 + (wg >> 3);
    const int t0 = (gwi >> 3) * 128;           // contiguous t per XCD
    const int n0 = (gwi & 7) * 128;            // n fastest
    const int b_local = blockIdx.y;

    const ushort* Bsh = ((n0 < 512) ? SEh : SOh) + (size_t)b_local * SE_E;
    const int kmax = (n0 < 512) ? KE : 512;    // odd-k basis has no K >= 512

    const int srow8 = tid >> 3;
    const int csrc = (((tid & 7) ^ ((tid >> 3) & 7))) * 8;
    const int arow = lane & 15;

    f32x4 acc[4][4] = {};
    char* pA = (char*)sA;
    char* pB = (char*)sB;

    for (int k0 = 0; k0 < kmax; k0 += 64) {
        #pragma unroll
        for (int q = 0; q < 4; ++q) {
            size_t ao = (size_t)(n0 + q * 32 + srow8) * KE + k0 + csrc;
            GLOAD_LDS16(Ab + ao, pA + q * 4096 + w * 1024);
            size_t bo = ((size_t)(k0 >> 6) * T_ + t0 + q * 32 + srow8) * 64 + csrc;
            GLOAD_LDS16(Bsh + bo, pB + q * 4096 + w * 1024);
        }
        __syncthreads();
        #pragma unroll
        for (int kh = 0; kh < 2; ++kh) {
            f16x8 a[4], b[4];
            #pragma unroll
            for (int i = 0; i < 4; ++i) {
                int row = wr * 64 + i * 16 + arow;
                int cc = (kh * 4 + g) ^ (row & 7);
                a[i] = *reinterpret_cast<const f16x8*>(&sA[row * 64 + cc * 8]);
            }
            #pragma unroll
            for (int j = 0; j < 4; ++j) {
                int row = wc * 64 + j * 16 + arow;
                int cc = (kh * 4 + g) ^ (row & 7);
                b[j] = *reinterpret_cast<const f16x8*>(&sB[row * 64 + cc * 8]);
            }
            #pragma unroll
            for (int i = 0; i < 4; ++i)
                #pragma unroll
                for (int j = 0; j < 4; ++j)
                    acc[i][j] = __builtin_amdgcn_mfma_f32_16x16x32_f16(a[i], b[j], acc[i][j], 0, 0, 0);
        }
        __syncthreads();
    }

    // epilogue: C row = n'', col = t; EO[b][t][n''] as fp16, 8B stores
    const int ccol = lane & 15;
    const int rbase = (lane >> 4) * 4;
    __half* eob = EO + (size_t)b_local * EO_E;
    #pragma unroll
    for (int i = 0; i < 4; ++i) {
        int nb = n0 + wr * 64 + i * 16 + rbase;
        #pragma unroll
        for (int j = 0; j < 4; ++j) {
            int t = t0 + wc * 64 + j * 16 + ccol;
            __half hv[4];
            hv[0] = __float2half(acc[i][j][0]);
            hv[1] = __float2half(acc[i][j][1]);
            hv[2] = __float2half(acc[i][j][2]);
            hv[3] = __float2half(acc[i][j][3]);
            *reinterpret_cast<short4*>(&eob[(size_t)t * NFFT + nb]) =
                *reinterpret_cast<short4*>(hv);
        }
    }
}

// ---------------- gather (x4 vectorized): window * butterfly * OLA / env -> out ----------------
__global__ void gather_kernel(const __half* __restrict__ EO,
                              const float* __restrict__ window,
                              float* __restrict__ out, int b0, int bcount) {
    int o0 = (blockIdx.x * 256 + threadIdx.x) * 4;
    int s = o0 + PAD;                    // s % 4 == 0
    int m = s >> 8, p = s & 255;         // p in {0,4,...,252}: 4 samples share m
    float env[4] = {1e-11f, 1e-11f, 1e-11f, 1e-11f};
    float wv[4][4]; int tv[4]; float sg[4];
    #pragma unroll
    for (int j = 0; j < 4; ++j) {
        int t = m - j;
        bool ok = (t >= 0) && (t < T_);
        tv[j] = ok ? t : 0;
        sg[j] = (j < 2) ? 1.f : -1.f;
        float4 w4 = ok ? *reinterpret_cast<const float4*>(&window[p + 256 * j])
                       : make_float4(0.f, 0.f, 0.f, 0.f);
        wv[j][0] = w4.x; wv[j][1] = w4.y; wv[j][2] = w4.z; wv[j][3] = w4.w;
        #pragma unroll
        for (int r = 0; r < 4; ++r) env[r] = fmaf(wv[j][r], wv[j][r], env[r]);
    }
    float inv[4];
    #pragma unroll
    for (int r = 0; r < 4; ++r) inv[r] = 1.0f / env[r];

    for (int bl = 0; bl < bcount; ++bl) {
        const __half* eo = EO + (size_t)bl * EO_E;
        float y[4] = {0.f, 0.f, 0.f, 0.f};
        #pragma unroll
        for (int j = 0; j < 4; ++j) {
            const __half* row = eo + (size_t)tv[j] * NFFT + p + 256 * (j & 1);
            ushort4 ue = *reinterpret_cast<const ushort4*>(row);
            ushort4 uo = *reinterpret_cast<const ushort4*>(row + 512);
            float e[4] = {h2f(ue.x), h2f(ue.y), h2f(ue.z), h2f(ue.w)};
            float od[4] = {h2f(uo.x), h2f(uo.y), h2f(uo.z), h2f(uo.w)};
            #pragma unroll
            for (int r = 0; r < 4; ++r)
                y[r] = fmaf(wv[j][r], fmaf(sg[j], od[r], e[r]), y[r]);
        }
        *reinterpret_cast<float4*>(&out[(size_t)(b0 + bl) * OUTB + o0]) =
            make_float4(y[0] * inv[0], y[1] * inv[1], y[2] * inv[2], y[3] * inv[3]);
    }
}

// ---------------- launch ----------------
extern "C" void kernel_launch(void* const* d_in, const int* in_sizes, int n_in,
                              void* d_out, int out_size, void* d_ws, size_t ws_size,
                              hipStream_t stream) {
    const float* x      = (const float*)d_in[0];
    const float* W      = (const float*)d_in[1];
    const float* bias   = (const float*)d_in[2];
    const float* window = (const float*)d_in[3];
    float* out = (float*)d_out;

    const size_t Ae  = (size_t)NFFT * KE;        //   589,824
    const size_t We  = (size_t)NW * H_;          //   294,912

    // Layout: [Ab|Wm|Wp|spec E,O (fp16)|EO(fp16)] ; xh (fp16) aliases EO (validated r12/r14).
    int bcount = B_;
    for (;;) {
        size_t need = (Ae + 2 * We + 2 * (size_t)bcount * SE_E) * sizeof(ushort)
                    + (size_t)bcount * EO_E * sizeof(__half);
        if (need <= ws_size || bcount == 1) break;
        bcount >>= 1;
    }

    ushort* Ab  = (ushort*)d_ws;
    ushort* Wm  = Ab + Ae;
    ushort* Wp  = Wm + We;
    ushort* SEh = Wp + We;
    ushort* SOh = SEh + (size_t)bcount * SE_E;
    __half* EO  = (__half*)(SOh + (size_t)bcount * SE_E);
    ushort* xhb = (ushort*)EO;                     // alias: xh lives in EO region

    basis_kernel<<<(NFFT * KE) / 256, 256, 0, stream>>>(Ab);
    prepw_kernel<<<(NW * H_ + 255) / 256, 256, 0, stream>>>(W, Wm, Wp);

    for (int b0 = 0; b0 < B_; b0 += bcount) {
        convx_kernel<<<(int)((size_t)bcount * T_ * H_ / 8 / 256), 256, 0, stream>>>(x, xhb, b0);
        nyq_kernel<<<dim3(T_ / 64, bcount), 256, 0, stream>>>(xhb, Wm, Wp, bias, SEh);
        dim3 ga(bcount * 256);
        gemm_a_mfma<<<ga, 256, 0, stream>>>(xhb, Wm, Wp, bias, SEh, SOh);
        dim3 ge(256, bcount);
        gemm_eo_mfma<<<ge, 256, 0, stream>>>(Ab, SEh, SOh, EO);
        gather_kernel<<<OUTB / 4 / 256, 256, 0, stream>>>(EO, window, out, b0, bcount);
    }
}

// Round 18
// 176.530 us; speedup vs baseline: 1.8009x; 1.0021x over previous
//
#include <hip/hip_runtime.h>
#include <hip/hip_fp16.h>
#include <math.h>

#define B_  8
#define T_  4096
#define H_  512
#define FREQ 513
#define NW  576            // padded f (9 tiles of 64)
#define KE  576            // spec K: interleaved [re,im], padded; 9 tiles of 64
#define NFFT 1024
#define HOP 256
#define PAD 384
#define OUTB 1048576
#define CLAMP_MAXV 100.0f
#define SE_E ((size_t)T_ * KE)     // spec elems per batch (fp16)
#define EO_E ((size_t)T_ * NFFT)   // EO elems per batch

typedef __attribute__((ext_vector_type(8))) _Float16 f16x8;
typedef __attribute__((ext_vector_type(4))) float f32x4;

__device__ inline ushort f2h(float v) {
    _Float16 h = (_Float16)v;
    ushort u; __builtin_memcpy(&u, &h, 2); return u;
}
__device__ inline float h2f(ushort u) {
    _Float16 h; __builtin_memcpy(&h, &u, 2); return (float)h;
}

#define GLOAD_LDS16(g, l) __builtin_amdgcn_global_load_lds( \
    (const __attribute__((address_space(1))) unsigned int*)(g), \
    (__attribute__((address_space(3))) unsigned int*)(l), 16, 0, 0)

// ---------------- basis (fp16): Ab[r][c]; r<512: E half (k=2kk), r>=512: O half (k=2kk+1) --------
__global__ void basis_kernel(ushort* __restrict__ Ab) {
    int idx = blockIdx.x * 256 + threadIdx.x;   // [0, 1024*576)
    int r = idx / KE, c = idx - r * KE;
    int np = (r < 512) ? r : (r - 512);
    int kk = c >> 1;
    int k = (r < 512) ? (2 * kk) : (2 * kk + 1);
    float v = 0.f;
    bool valid = (r < 512) ? (kk <= 256) : (kk <= 255);
    if (valid) {
        int m = (np * k) & (NFFT - 1);
        float a = (float)m * 6.135923151542565e-3f;       // 2*pi/1024
        float sc = ((k == 0) || (k == 512)) ? (1.0f / NFFT) : (2.0f / NFFT);
        v = ((c & 1) ? -sinf(a) : cosf(a)) * sc;
    }
    Ab[idx] = f2h(v);
}

// ---------------- W prep (fp16): Wm/Wp [f(576)][k(512)] ----------------
__global__ void prepw_kernel(const float* __restrict__ W,
                             ushort* __restrict__ Wm, ushort* __restrict__ Wp) {
    int idx = blockIdx.x * 256 + threadIdx.x;
    if (idx >= NW * H_) return;
    int k = idx / NW, f = idx - k * NW;
    float vm = 0.f, vp = 0.f;
    if (f < FREQ) {
        vm = W[(size_t)k * (2 * FREQ) + f];
        vp = W[(size_t)k * (2 * FREQ) + FREQ + f];
    }
    size_t dst = (size_t)f * H_ + k;
    Wm[dst] = f2h(vm);
    Wp[dst] = f2h(vp);
}

// ---------------- x conversion (fp16, per bcount-chunk) ----------------
__global__ void convx_kernel(const float* __restrict__ x, ushort* __restrict__ xh, int b0) {
    size_t i8 = ((size_t)blockIdx.x * 256 + threadIdx.x) * 8;
    const float* xp = x + (size_t)b0 * T_ * H_ + i8;
    float4 v0 = *reinterpret_cast<const float4*>(xp);
    float4 v1 = *reinterpret_cast<const float4*>(xp + 4);
    float xv[8];
    *reinterpret_cast<float4*>(&xv[0]) = v0;
    *reinterpret_cast<float4*>(&xv[4]) = v1;
    ushort h[8];
    #pragma unroll
    for (int e = 0; e < 8; ++e) h[e] = f2h(xv[e]);
    *reinterpret_cast<ushort4*>(xh + i8)     = make_ushort4(h[0], h[1], h[2], h[3]);
    *reinterpret_cast<ushort4*>(xh + i8 + 4) = make_ushort4(h[4], h[5], h[6], h[7]);
}

// ---------------- nyquist-ish column f=512: fp32 GEMV -> SE tile 8 ----------------
__global__ void nyq_kernel(const ushort* __restrict__ xh,
                           const ushort* __restrict__ Wm, const ushort* __restrict__ Wp,
                           const float* __restrict__ bias,
                           ushort* __restrict__ SEh) {
    __shared__ ushort sW[1024];
    const int tid = threadIdx.x;
    const int b_local = blockIdx.y;
    const int t0 = blockIdx.x * 64;

    if (tid < 128) {
        const ushort* src = ((tid < 64) ? &Wm[(size_t)512 * H_] : &Wp[(size_t)512 * H_]);
        int base = (tid < 64) ? 0 : 512;
        int i = (tid & 63) * 8;
        *reinterpret_cast<ushort4*>(&sW[base + i])     = *reinterpret_cast<const ushort4*>(&src[i]);
        *reinterpret_cast<ushort4*>(&sW[base + i + 4]) = *reinterpret_cast<const ushort4*>(&src[i + 4]);
    }
    __syncthreads();

    const int tl = tid >> 2;
    const int q = tid & 3;
    const ushort* xr = xh + ((size_t)b_local * T_ + t0 + tl) * H_ + q * 128;
    float accm = 0.f, accp = 0.f;
    #pragma unroll
    for (int i = 0; i < 128; i += 8) {
        ushort4 xa = *reinterpret_cast<const ushort4*>(&xr[i]);
        ushort4 xb = *reinterpret_cast<const ushort4*>(&xr[i + 4]);
        ushort4 ma = *reinterpret_cast<const ushort4*>(&sW[q * 128 + i]);
        ushort4 mb = *reinterpret_cast<const ushort4*>(&sW[q * 128 + i + 4]);
        ushort4 pa = *reinterpret_cast<const ushort4*>(&sW[512 + q * 128 + i]);
        ushort4 pb = *reinterpret_cast<const ushort4*>(&sW[512 + q * 128 + i + 4]);
        ushort xs[8] = {xa.x, xa.y, xa.z, xa.w, xb.x, xb.y, xb.z, xb.w};
        ushort ms[8] = {ma.x, ma.y, ma.z, ma.w, mb.x, mb.y, mb.z, mb.w};
        ushort ps[8] = {pa.x, pa.y, pa.z, pa.w, pb.x, pb.y, pb.z, pb.w};
        #pragma unroll
        for (int e = 0; e < 8; ++e) {
            float xv = h2f(xs[e]);
            accm = fmaf(xv, h2f(ms[e]), accm);
            accp = fmaf(xv, h2f(ps[e]), accp);
        }
    }
    accm += __shfl_down(accm, 2); accm += __shfl_down(accm, 1);
    accp += __shfl_down(accp, 2); accp += __shfl_down(accp, 1);

    ushort vals[16] = {0};
    if (q == 0) {
        float mag = fminf(__expf(accm + bias[512]), CLAMP_MAXV);
        float phv = accp + bias[FREQ + 512];
        float sp, cp; __sincosf(phv, &sp, &cp);
        vals[0] = f2h(mag * cp);
        vals[1] = f2h(mag * sp);
    }
    ushort* drow = SEh + (size_t)b_local * SE_E + (size_t)8 * T_ * 64
                 + (size_t)(t0 + tl) * 64 + q * 16;
    *reinterpret_cast<ushort4*>(drow)      = make_ushort4(vals[0], vals[1], vals[2], vals[3]);
    *reinterpret_cast<ushort4*>(drow + 4)  = make_ushort4(vals[4], vals[5], vals[6], vals[7]);
    *reinterpret_cast<ushort4*>(drow + 8)  = make_ushort4(vals[8], vals[9], vals[10], vals[11]);
    *reinterpret_cast<ushort4*>(drow + 12) = make_ushort4(vals[12], vals[13], vals[14], vals[15]);
}

// ---------------- GEMM A (fp16 MFMA, 2-phase dbuf): tile 128t x 64f, BK=32 ----------------
// grid: 1D bcount*256, XCD-swizzled (f fastest). LDS 32KB dbuf. 16 MFMA/step, 16 steps.
__global__ __launch_bounds__(256) void gemm_a_mfma(
    const ushort* __restrict__ xh,
    const ushort* __restrict__ Wm, const ushort* __restrict__ Wp,
    const float* __restrict__ bias,
    ushort* __restrict__ SEh, ushort* __restrict__ SOh)
{
    // ushort idx: X buf b @ b*4096 [128x32]; Wm buf b @ 8192+b*2048 [64x32]; Wp @ 12288+b*2048
    __shared__ __attribute__((aligned(16))) ushort SH[16384];

    const int tid = threadIdx.x;
    const int lane = tid & 63;
    const int w = tid >> 6;
    const int wr = w >> 1, wc = w & 1;
    const int g = lane >> 4;

    const int nwg = gridDim.x;
    const int wg = blockIdx.x;
    const int gwi = (wg & 7) * (nwg >> 3) + (wg >> 3);
    const int m0 = (gwi >> 3) * 128;
    const int f0 = (gwi & 7) * 64;

    const int rl = tid >> 2;                                  // 0..63 (staging row)
    const int swz = ((tid & 3) ^ ((tid >> 3) & 3)) * 8;       // pre-swizzled src chunk
    const int arow = lane & 15;

    f32x4 accM[4][2] = {};
    f32x4 accP[4][2] = {};
    char* pSH = (char*)SH;

    #define STAGE_A(b, k0) do { \
        GLOAD_LDS16(xh + (size_t)(m0 + rl) * H_ + (k0) + swz,       pSH + (b) * 8192 + w * 1024); \
        GLOAD_LDS16(xh + (size_t)(m0 + 64 + rl) * H_ + (k0) + swz,  pSH + (b) * 8192 + 4096 + w * 1024); \
        GLOAD_LDS16(Wm + (size_t)(f0 + rl) * H_ + (k0) + swz,       pSH + 16384 + (b) * 4096 + w * 1024); \
        GLOAD_LDS16(Wp + (size_t)(f0 + rl) * H_ + (k0) + swz,       pSH + 24576 + (b) * 4096 + w * 1024); \
    } while (0)

    STAGE_A(0, 0);
    __syncthreads();
    #pragma unroll 2
    for (int step = 0; step < 16; ++step) {
        const int cur = step & 1;
        if (step < 15) STAGE_A(cur ^ 1, (step + 1) * 32);
        f16x8 ax[4], wm[2], wp[2];
        #pragma unroll
        for (int i = 0; i < 4; ++i) {
            int row = wr * 64 + i * 16 + arow;
            int cc = g ^ ((row >> 1) & 3);
            ax[i] = *reinterpret_cast<const f16x8*>(&SH[cur * 4096 + row * 32 + cc * 8]);
        }
        #pragma unroll
        for (int j = 0; j < 2; ++j) {
            int row = wc * 32 + j * 16 + arow;
            int cc = g ^ ((row >> 1) & 3);
            wm[j] = *reinterpret_cast<const f16x8*>(&SH[8192 + cur * 2048 + row * 32 + cc * 8]);
            wp[j] = *reinterpret_cast<const f16x8*>(&SH[12288 + cur * 2048 + row * 32 + cc * 8]);
        }
        #pragma unroll
        for (int i = 0; i < 4; ++i)
            #pragma unroll
            for (int j = 0; j < 2; ++j) {
                accM[i][j] = __builtin_amdgcn_mfma_f32_16x16x32_f16(ax[i], wm[j], accM[i][j], 0, 0, 0);
                accP[i][j] = __builtin_amdgcn_mfma_f32_16x16x32_f16(ax[i], wp[j], accP[i][j], 0, 0, 0);
            }
        __syncthreads();
    }
    #undef STAGE_A

    // ---- epilogue: nonlinearity (all f live), then 2-pass (SE, SO) LDS transpose ----
    const int ccol = lane & 15;
    const int rbase = (lane >> 4) * 4;
    const int b_local = m0 >> 12;
    const int t00blk = m0 & (T_ - 1);
    const size_t specoff = (size_t)b_local * SE_E;
    const size_t tilebase = (size_t)(f0 >> 6) * T_ * 64;

    #pragma unroll
    for (int j = 0; j < 2; ++j) {
        int f = f0 + wc * 32 + j * 16 + ccol;      // <= 511, always live
        float bm = bias[f];
        float bp = bias[FREQ + f];
        #pragma unroll
        for (int i = 0; i < 4; ++i)
            #pragma unroll
            for (int r = 0; r < 4; ++r) {
                float mag = fminf(__expf(accM[i][j][r] + bm), CLAMP_MAXV);
                float phv = accP[i][j][r] + bp;
                float sp, cp; __sincosf(phv, &sp, &cp);
                accM[i][j][r] = mag * cp;
                accP[i][j][r] = mag * sp;
            }
    }

    const int par_mine = ccol & 1;
    const int row0 = tid >> 3;           // 0..31
    const int c8 = (tid & 7) * 8;
    #pragma unroll
    for (int pass = 0; pass < 2; ++pass) {
        if (par_mine == pass) {
            #pragma unroll
            for (int j = 0; j < 2; ++j) {
                int u = wc * 32 + j * 16 + ccol;
                int kl = u & ~1;
                #pragma unroll
                for (int i = 0; i < 4; ++i) {
                    #pragma unroll
                    for (int r = 0; r < 4; ++r) {
                        int tl = wr * 64 + i * 16 + rbase + r;
                        *reinterpret_cast<ushort2*>(&SH[tl * 72 + kl]) =
                            make_ushort2(f2h(accM[i][j][r]), f2h(accP[i][j][r]));
                    }
                }
            }
        }
        __syncthreads();
        ushort* d = (pass ? SOh : SEh) + specoff + tilebase;
        #pragma unroll
        for (int q2 = 0; q2 < 4; ++q2) {
            int row = q2 * 32 + row0;
            ushort4 v0 = *reinterpret_cast<const ushort4*>(&SH[row * 72 + c8]);
            ushort4 v1 = *reinterpret_cast<const ushort4*>(&SH[row * 72 + c8 + 4]);
            ushort* dp = &d[(size_t)(t00blk + row) * 64 + c8];
            *reinterpret_cast<ushort4*>(dp) = v0;
            *reinterpret_cast<ushort4*>(dp + 4) = v1;
        }
        if (pass == 0) __syncthreads();
    }
}

// ---------------- stage 1 GEMM (fp16 MFMA, 2-phase dbuf): EO = basis.spec ----------------
// grid: (256, bcount), XCD-swizzled. Tile 128n x 128t, BK=32; 16 MFMA/step; E 18 / O 16 steps.
__global__ __launch_bounds__(256) void gemm_eo_mfma(
    const ushort* __restrict__ Ab,
    const ushort* __restrict__ SEh, const ushort* __restrict__ SOh,
    __half* __restrict__ EO)
{
    // ushort idx: A buf b @ b*4096 [128x32]; B buf b @ 8192 + b*4096 [128x32]
    __shared__ __attribute__((aligned(16))) ushort SH[16384];
    const int tid = threadIdx.x;
    const int lane = tid & 63;
    const int w = tid >> 6;
    const int wr = w >> 1, wc = w & 1;
    const int g = lane >> 4;

    const int wg = blockIdx.x;                 // 256 = 32t x 8n, % 8 == 0
    const int gwi = (wg & 7) * 32 + (wg >> 3);
    const int t0 = (gwi >> 3) * 128;           // contiguous t per XCD
    const int n0 = (gwi & 7) * 128;            // n fastest
    const int b_local = blockIdx.y;

    const ushort* Bsh = ((n0 < 512) ? SEh : SOh) + (size_t)b_local * SE_E;
    const int nsteps = (n0 < 512) ? (KE / 32) : (512 / 32);   // 18 or 16 (both even)

    const int rl = tid >> 2;
    const int swz = ((tid & 3) ^ ((tid >> 3) & 3)) * 8;
    const int arow = lane & 15;

    f32x4 acc[4][4] = {};
    char* pSH = (char*)SH;

    #define STAGE_E(b, k0) do { \
        GLOAD_LDS16(Ab + (size_t)(n0 + rl) * KE + (k0) + swz,       pSH + (b) * 8192 + w * 1024); \
        GLOAD_LDS16(Ab + (size_t)(n0 + 64 + rl) * KE + (k0) + swz,  pSH + (b) * 8192 + 4096 + w * 1024); \
        GLOAD_LDS16(Bsh + ((size_t)((k0) >> 6) * T_ + t0 + rl) * 64 + ((k0) & 32) + swz,      pSH + 16384 + (b) * 8192 + w * 1024); \
        GLOAD_LDS16(Bsh + ((size_t)((k0) >> 6) * T_ + t0 + 64 + rl) * 64 + ((k0) & 32) + swz, pSH + 16384 + (b) * 8192 + 4096 + w * 1024); \
    } while (0)

    STAGE_E(0, 0);
    __syncthreads();
    #pragma unroll 2
    for (int step = 0; step < nsteps; ++step) {
        const int cur = step & 1;
        if (step + 1 < nsteps) STAGE_E(cur ^ 1, (step + 1) * 32);
        f16x8 a[4], b[4];
        #pragma unroll
        for (int i = 0; i < 4; ++i) {
            int row = wr * 64 + i * 16 + arow;
            int cc = g ^ ((row >> 1) & 3);
            a[i] = *reinterpret_cast<const f16x8*>(&SH[cur * 4096 + row * 32 + cc * 8]);
        }
        #pragma unroll
        for (int j = 0; j < 4; ++j) {
            int row = wc * 64 + j * 16 + arow;
            int cc = g ^ ((row >> 1) & 3);
            b[j] = *reinterpret_cast<const f16x8*>(&SH[8192 + cur * 4096 + row * 32 + cc * 8]);
        }
        #pragma unroll
        for (int i = 0; i < 4; ++i)
            #pragma unroll
            for (int j = 0; j < 4; ++j)
                acc[i][j] = __builtin_amdgcn_mfma_f32_16x16x32_f16(a[i], b[j], acc[i][j], 0, 0, 0);
        __syncthreads();
    }
    #undef STAGE_E

    // epilogue: C row = n'', col = t; EO[b][t][n''] as fp16, 8B stores
    const int ccol = lane & 15;
    const int rbase = (lane >> 4) * 4;
    __half* eob = EO + (size_t)b_local * EO_E;
    #pragma unroll
    for (int i = 0; i < 4; ++i) {
        int nb = n0 + wr * 64 + i * 16 + rbase;
        #pragma unroll
        for (int j = 0; j < 4; ++j) {
            int t = t0 + wc * 64 + j * 16 + ccol;
            __half hv[4];
            hv[0] = __float2half(acc[i][j][0]);
            hv[1] = __float2half(acc[i][j][1]);
            hv[2] = __float2half(acc[i][j][2]);
            hv[3] = __float2half(acc[i][j][3]);
            *reinterpret_cast<short4*>(&eob[(size_t)t * NFFT + nb]) =
                *reinterpret_cast<short4*>(hv);
        }
    }
}

// ---------------- gather (x4 vectorized): window * butterfly * OLA / env -> out ----------------
__global__ void gather_kernel(const __half* __restrict__ EO,
                              const float* __restrict__ window,
                              float* __restrict__ out, int b0, int bcount) {
    int o0 = (blockIdx.x * 256 + threadIdx.x) * 4;
    int s = o0 + PAD;
    int m = s >> 8, p = s & 255;
    float env[4] = {1e-11f, 1e-11f, 1e-11f, 1e-11f};
    float wv[4][4]; int tv[4]; float sg[4];
    #pragma unroll
    for (int j = 0; j < 4; ++j) {
        int t = m - j;
        bool ok = (t >= 0) && (t < T_);
        tv[j] = ok ? t : 0;
        sg[j] = (j < 2) ? 1.f : -1.f;
        float4 w4 = ok ? *reinterpret_cast<const float4*>(&window[p + 256 * j])
                       : make_float4(0.f, 0.f, 0.f, 0.f);
        wv[j][0] = w4.x; wv[j][1] = w4.y; wv[j][2] = w4.z; wv[j][3] = w4.w;
        #pragma unroll
        for (int r = 0; r < 4; ++r) env[r] = fmaf(wv[j][r], wv[j][r], env[r]);
    }
    float inv[4];
    #pragma unroll
    for (int r = 0; r < 4; ++r) inv[r] = 1.0f / env[r];

    for (int bl = 0; bl < bcount; ++bl) {
        const __half* eo = EO + (size_t)bl * EO_E;
        float y[4] = {0.f, 0.f, 0.f, 0.f};
        #pragma unroll
        for (int j = 0; j < 4; ++j) {
            const __half* row = eo + (size_t)tv[j] * NFFT + p + 256 * (j & 1);
            ushort4 ue = *reinterpret_cast<const ushort4*>(row);
            ushort4 uo = *reinterpret_cast<const ushort4*>(row + 512);
            float e[4] = {h2f(ue.x), h2f(ue.y), h2f(ue.z), h2f(ue.w)};
            float od[4] = {h2f(uo.x), h2f(uo.y), h2f(uo.z), h2f(uo.w)};
            #pragma unroll
            for (int r = 0; r < 4; ++r)
                y[r] = fmaf(wv[j][r], fmaf(sg[j], od[r], e[r]), y[r]);
        }
        *reinterpret_cast<float4*>(&out[(size_t)(b0 + bl) * OUTB + o0]) =
            make_float4(y[0] * inv[0], y[1] * inv[1], y[2] * inv[2], y[3] * inv[3]);
    }
}

// ---------------- launch ----------------
extern "C" void kernel_launch(void* const* d_in, const int* in_sizes, int n_in,
                              void* d_out, int out_size, void* d_ws, size_t ws_size,
                              hipStream_t stream) {
    const float* x      = (const float*)d_in[0];
    const float* W      = (const float*)d_in[1];
    const float* bias   = (const float*)d_in[2];
    const float* window = (const float*)d_in[3];
    float* out = (float*)d_out;

    const size_t Ae  = (size_t)NFFT * KE;        //   589,824
    const size_t We  = (size_t)NW * H_;          //   294,912

    // Layout: [Ab|Wm|Wp|spec E,O (fp16)|EO(fp16)] ; xh (fp16) aliases EO (validated r12/r14).
    int bcount = B_;
    for (;;) {
        size_t need = (Ae + 2 * We + 2 * (size_t)bcount * SE_E) * sizeof(ushort)
                    + (size_t)bcount * EO_E * sizeof(__half);
        if (need <= ws_size || bcount == 1) break;
        bcount >>= 1;
    }

    ushort* Ab  = (ushort*)d_ws;
    ushort* Wm  = Ab + Ae;
    ushort* Wp  = Wm + We;
    ushort* SEh = Wp + We;
    ushort* SOh = SEh + (size_t)bcount * SE_E;
    __half* EO  = (__half*)(SOh + (size_t)bcount * SE_E);
    ushort* xhb = (ushort*)EO;                     // alias: xh lives in EO region

    basis_kernel<<<(NFFT * KE) / 256, 256, 0, stream>>>(Ab);
    prepw_kernel<<<(NW * H_ + 255) / 256, 256, 0, stream>>>(W, Wm, Wp);

    for (int b0 = 0; b0 < B_; b0 += bcount) {
        convx_kernel<<<(int)((size_t)bcount * T_ * H_ / 8 / 256), 256, 0, stream>>>(x, xhb, b0);
        nyq_kernel<<<dim3(T_ / 64, bcount), 256, 0, stream>>>(xhb, Wm, Wp, bias, SEh);
        dim3 ga(bcount * 256);
        gemm_a_mfma<<<ga, 256, 0, stream>>>(xhb, Wm, Wp, bias, SEh, SOh);
        dim3 ge(256, bcount);
        gemm_eo_mfma<<<ge, 256, 0, stream>>>(Ab, SEh, SOh, EO);
        gather_kernel<<<OUTB / 4 / 256, 256, 0, stream>>>(EO, window, out, b0, bcount);
    }
}